// Round 6
// baseline (1217.212 us; speedup 1.0000x reference)
//
#include <hip/hip_runtime.h>
#include <math.h>

#define M_PTS 29696
#define KCL 100
#define NZ_DIM 32

typedef _Float16 h8 __attribute__((ext_vector_type(8)));
typedef _Float16 h4 __attribute__((ext_vector_type(4)));
typedef float f4 __attribute__((ext_vector_type(4)));

// async global->LDS, 16B per lane; LDS dest is wave-uniform base + lane*16
__device__ __forceinline__ void load_lds16(const void* g, void* l) {
    __builtin_amdgcn_global_load_lds(
        (const __attribute__((address_space(1))) void*)g,
        (__attribute__((address_space(3))) void*)l, 16, 0, 0);
}

// ---------------- batched weight transpose+split (+ folded accumulator zeroing) ----------------
// W (KxN) fp32 -> WTh/WTl (NxK) f16 hi/lo planes, all 8 weights in one launch.
struct PrepW {
    const float* W[8];
    _Float16* Th[8];
    _Float16* Tl[8];
    int K[8];
    int N[8];
    int off[9];   // cumulative 32x32-tile counts, off[0]=0
};

__global__ __launch_bounds__(256)
void prep_weights(PrepW a, float* __restrict__ Zf, float* __restrict__ U,
                  int* __restrict__ CNT, double* __restrict__ DBL)
{
    __shared__ float t[32][33];
    const int bid = blockIdx.x;
    const int tid = threadIdx.x;

    // folded zeroing: first 928 blocks cover Zf (29696*32 floats) exactly
    if (bid < (M_PTS*NZ_DIM/4/256)) {
        const size_t zi = ((size_t)bid*256 + tid)*4;
        *(float4*)(Zf + zi) = make_float4(0.0f, 0.0f, 0.0f, 0.0f);
    }
    if (bid == 0) {
        if (tid < 128) { U[tid] = 0.0f; CNT[tid] = 0; }   // incl. last-block counters @126/127
        if (tid < 8) DBL[tid] = 0.0;
    }

    int w = 0;
    #pragma unroll
    for (int i = 1; i < 8; ++i) w += (bid >= a.off[i]);
    const int local = bid - a.off[w];
    const int K = a.K[w], N = a.N[w];
    const int tx = N >> 5;                       // tiles along N (power of 2)
    const int sh = __builtin_ctz(tx);
    const int n0 = (local & (tx - 1)) * 32, k0 = (local >> sh) * 32;
    const float* W = a.W[w];
    _Float16* WTh = a.Th[w];
    _Float16* WTl = a.Tl[w];

    {
        int r = tid / 8, c = (tid % 8) * 4;
        const float4 v = *(const float4*)(W + (size_t)(k0 + r) * N + n0 + c);
        t[r][c+0] = v.x; t[r][c+1] = v.y; t[r][c+2] = v.z; t[r][c+3] = v.w;
    }
    __syncthreads();
    {
        int r = tid / 8, c = (tid % 8) * 4;   // r = n idx, c = k idx
        h4 hi, lo;
        #pragma unroll
        for (int u = 0; u < 4; ++u) {
            float f = t[c+u][r];
            _Float16 h = (_Float16)f;
            hi[u] = h; lo[u] = (_Float16)(f - (float)h);
        }
        *(h4*)(WTh + (size_t)(n0 + r) * K + k0 + c) = hi;
        *(h4*)(WTl + (size_t)(n0 + r) * K + k0 + c) = lo;
    }
}

// ---------------- MFMA GEMM, async double-buffered LDS ----------------
// A planes: MxK f16; B planes: NxK f16. C = act(A@B^T + bias).
// TERMS=3: split-precision (hi*hi + hi*lo + lo*hi), PL=2 planes staged.
// TERMS=1: plain f16, PL=1.
// MODE 0: write hi+lo. MODE 1: hi + fp32. MODE 2: fused re-loss. MODE 3: hi only.
// MODE 4: no C write; fused z-projection: atomicAdd(Cf, relu(C+bias) @ Wz^T chunk),
//         with Ch/Cl reinterpreted as Wz^T hi/lo planes (32 x N layout, stride N).
// MODE 5: fused-A decoder: A = relu(Z @ Wd1 + bd1) computed in-kernel per K-step.
//         Ahp = Zf (Mx32 fp32, cast), Cl = bz (fp32, cast), Alp = Wd1h, Xref = bd1.
// ASRC 1: A staged from fp32 Xref (MxK), split hi/lo in-kernel (reg-staged,
//         T14 async split: load early, ds_write after barrier). Same LDS layout.
template<int WM,int WN,int TM,int TN,bool RELU,int MODE,int TERMS,int ASRC=0>
__global__ __launch_bounds__(WM*WN*64)
void gemm_sp(const _Float16* __restrict__ Ahp, const _Float16* __restrict__ Alp,
             const _Float16* __restrict__ Bhp, const _Float16* __restrict__ Blp,
             const float* __restrict__ bias,
             _Float16* __restrict__ Ch, _Float16* __restrict__ Cl,
             float* __restrict__ Cf, const float* __restrict__ Xref,
             double* __restrict__ loss_acc,
             int M, int N, int K)
{
    constexpr int BM = WM*TM*16, BN = WN*TN*16, NW = WM*WN;
    constexpr int PL = (TERMS == 3) ? 2 : 1;
    constexpr int CA = BM/16, CB = BN/16;          // 1KB chunks
    constexpr int STRIDE = PL*(BM+BN)*32;          // halves per stage
    // per-wave vmcnt-counted issues per stage (uniform across waves).
    // ASRC=1: the 4 A-reg float4 loads occupy the same count the A asyncs did.
    constexpr int NPW = ((MODE == 5) ? 1 : (CA/NW)*PL)
                      + ((CB >= NW) ? (CB/NW) : 1)*PL;
    constexpr int NPW_B = ((CB >= NW) ? (CB/NW) : 1)*PL;   // B-only in-flight bound
    static_assert(ASRC == 0 || (TERMS == 3 && (CA/NW) == 2 && MODE == 0),
                  "ASRC=1 path sized for the L1 config");
    // MODE5 extra LDS: wd1 chunk dbuf (2x1024 halves) + bd1 bias (2048 f32 = 4096 halves)
    constexpr int EXTRA = (MODE == 5) ? (2048 + 4096) : 0;
    __shared__ __align__(16) _Float16 smem[2*STRIDE + EXTRA];

    const int tid = threadIdx.x;
    const int wave = tid >> 6, lane = tid & 63;
    const int wm = wave / WN, wn = wave % WN;
    const int lrow = lane & 15, lq = lane >> 4;
    const int sw = (lrow >> 1) & 3;                // bank swizzle
    const int lr4 = lane >> 2, lc4 = lane & 3;     // staging row-in-chunk / 16B col
    const int bm0 = blockIdx.y * BM, bn0 = blockIdx.x * BN;

    f4 acc[TM][TN];
    #pragma unroll
    for (int i = 0; i < TM; ++i)
        #pragma unroll
        for (int j = 0; j < TN; ++j)
            acc[i][j] = (f4)0.0f;

    auto stage = [&](int s, int k0) {
        _Float16* base = smem + s*STRIDE;
        if constexpr (MODE == 5) {
            // Wd1 chunk for this K-step: 32 rows x 32 halves; per wave its wn-half (1KB).
            // Issued FIRST so the mid-loop vmcnt(NPW-1) guarantees its arrival.
            int r_in = lane >> 2;                        // 0..15
            int gk = (lane & 3) ^ ((r_in >> 1) & 3);     // same k-group swizzle as A staging
            load_lds16(Alp + (size_t)(k0 + wn*16 + r_in)*32 + gk*8,
                       smem + 2*STRIDE + s*1024 + wn*512);
        } else if constexpr (ASRC == 1) {
            // A staged via reg path (see stageA_*); nothing async here.
        } else {
            #pragma unroll
            for (int c = wave; c < CA; c += NW) {
                int r = c*16 + lr4;
                int g = lc4 ^ ((r >> 1) & 3);
                size_t goff = (size_t)(bm0 + r)*K + k0 + g*8;
                load_lds16(Ahp + goff, base + c*512);
                if (PL == 2) load_lds16(Alp + goff, base + BM*32 + c*512);
            }
        }
        if (CB >= NW) {
            #pragma unroll
            for (int c = wave; c < CB; c += NW) {
                int r = c*16 + lr4;
                int g = lc4 ^ ((r >> 1) & 3);
                size_t goff = (size_t)(bn0 + r)*K + k0 + g*8;
                load_lds16(Bhp + goff, base + PL*BM*32 + c*512);
                if (PL == 2) load_lds16(Blp + goff, base + PL*BM*32 + BN*32 + c*512);
            }
        } else {  // fewer B chunks than waves: duplicate issues keep counts uniform
            int c = wave % CB;
            int r = c*16 + lr4;
            int g = lc4 ^ ((r >> 1) & 3);
            size_t goff = (size_t)(bn0 + r)*K + k0 + g*8;
            load_lds16(Bhp + goff, base + PL*BM*32 + c*512);
            if (PL == 2) load_lds16(Blp + goff, base + PL*BM*32 + BN*32 + c*512);
        }
    };

    // ---- ASRC=1: fp32 A-split staging (reg-staged, async-split) ----
    auto stageA_load = [&](int k0, float4 (&ar)[4]) {
        if constexpr (ASRC == 1) {
            #pragma unroll
            for (int u = 0; u < 2; ++u) {              // chunks c = wave + u*NW
                int c = wave + u*NW;
                int r = c*16 + lr4;
                int g = lc4 ^ ((r >> 1) & 3);
                const float* src = Xref + (size_t)(bm0 + r)*K + k0 + g*8;
                ar[u*2+0] = *(const float4*)(src);
                ar[u*2+1] = *(const float4*)(src + 4);
            }
        }
    };
    auto stageA_write = [&](int s, const float4 (&ar)[4]) {
        if constexpr (ASRC == 1) {
            _Float16* base = smem + s*STRIDE;
            #pragma unroll
            for (int u = 0; u < 2; ++u) {
                int c = wave + u*NW;
                float fv[8] = {ar[u*2].x, ar[u*2].y, ar[u*2].z, ar[u*2].w,
                               ar[u*2+1].x, ar[u*2+1].y, ar[u*2+1].z, ar[u*2+1].w};
                h8 hi, lo;
                #pragma unroll
                for (int q = 0; q < 8; ++q) {
                    _Float16 h = (_Float16)fv[q];
                    hi[q] = h; lo[q] = (_Float16)(fv[q] - (float)h);
                }
                // identical layout to the async path: chunk base + lane*16B
                *(h8*)(base + c*512 + lane*8) = hi;
                *(h8*)(base + BM*32 + c*512 + lane*8) = lo;
            }
        }
    };

    // MODE5: z fragments (loop-invariant A rows of the inner d1 matmul), built from
    // fp32 Zf + bz (bitwise-identical to the old finish_z staged f16 plane).
    h8 zfr[(MODE == 5) ? TM : 1];
    auto computeA = [&](int ds, int s) {
        if constexpr (MODE == 5) {
            const _Float16* wslot = smem + 2*STRIDE + ds*1024 + wn*512;
            const float* bds = (const float*)(smem + 2*STRIDE + 2048);
            h8 wf = *(const h8*)(wslot + lrow*32 + ((lq ^ sw)*8));
            float bv = bds[s*32 + wn*16 + lrow];
            _Float16* areg = smem + ds*STRIDE;
            const int kc = wn*16 + lrow;               // d1-col within the 32-chunk
            #pragma unroll
            for (int i2 = 0; i2 < TM; ++i2) {
                f4 cc = __builtin_amdgcn_mfma_f32_16x16x32_f16(zfr[i2], wf, (f4)0.0f, 0, 0, 0);
                int cch = wm*TM + i2;
                #pragma unroll
                for (int r = 0; r < 4; ++r) {
                    float v = fmaxf(cc[r] + bv, 0.0f);
                    int r16 = lq*4 + r;
                    areg[cch*512 + r16*32 + (((kc >> 3) ^ ((r16 >> 1) & 3))*8) + (kc & 7)]
                        = (_Float16)v;
                }
            }
        }
    };

    float4 ar0[4];
    if constexpr (ASRC == 1) stageA_load(0, ar0);      // oldest vmcnt entries
    if constexpr (MODE == 5) {
        // stage bd1 -> LDS (2048 f32 = 8 chunks of 1KB), before stage(0,0)
        #pragma unroll
        for (int c = wave; c < 8; c += NW)
            load_lds16(Xref + c*256 + lane*4, smem + 2*STRIDE + 2048 + c*512);
        const float* zf32 = (const float*)Ahp;
        const float* bz32 = (const float*)Cl;
        float4 b0 = *(const float4*)(bz32 + lq*8);
        float4 b1 = *(const float4*)(bz32 + lq*8 + 4);
        float bb[8] = {b0.x,b0.y,b0.z,b0.w,b1.x,b1.y,b1.z,b1.w};
        #pragma unroll
        for (int i2 = 0; i2 < TM; ++i2) {
            const float* zsrc = zf32 + (size_t)(bm0 + (wm*TM + i2)*16 + lrow)*32 + lq*8;
            float4 z0 = *(const float4*)(zsrc);
            float4 z1 = *(const float4*)(zsrc + 4);
            float zz[8] = {z0.x,z0.y,z0.z,z0.w,z1.x,z1.y,z1.z,z1.w};
            #pragma unroll
            for (int q = 0; q < 8; ++q) zfr[i2][q] = (_Float16)(zz[q] + bb[q]);
        }
    }
    stage(0, 0);
    if constexpr (ASRC == 1) {
        __builtin_amdgcn_s_waitcnt(0x0F70 | NPW_B);    // A-reg(0) landed; B(0) may fly
        stageA_write(0, ar0);
        asm volatile("s_waitcnt lgkmcnt(0)" ::: "memory");  // publish before 1st barrier
    }
    if constexpr (MODE == 5) {
        __builtin_amdgcn_s_waitcnt(0x0F70);            // vmcnt(0): bias+W(0)+B(0) landed
        __builtin_amdgcn_s_barrier();
        computeA(0, 0);                                // A(0) into stage-0 A region
        asm volatile("s_waitcnt lgkmcnt(0)" ::: "memory");
        __builtin_amdgcn_s_barrier();                  // A(0) visible to all waves
    }

    const int steps = K >> 5;
    for (int i = 0; i < steps; ++i) {
        const int sel = i & 1;
        float4 arn[4];
        if (i + 1 < steps) {
            if constexpr (ASRC == 1) stageA_load((i + 1) << 5, arn);
            stage(sel ^ 1, (i + 1) << 5);                 // prefetch next stage
            __builtin_amdgcn_s_waitcnt(0x0F70 | NPW);     // drain current stage only
        } else {
            __builtin_amdgcn_s_waitcnt(0x0F70);
        }
        __builtin_amdgcn_s_barrier();                     // all waves' data visible

        const _Float16* base = smem + sel*STRIDE;
        h8 ah[TM], al[TM], bh[TN], bl[TN];
        #pragma unroll
        for (int i2 = 0; i2 < TM; ++i2) {
            int row = (wm*TM + i2)*16 + lrow;
            int off = row*32 + ((lq ^ sw)*8);
            ah[i2] = *(const h8*)(base + off);
            if (PL == 2) al[i2] = *(const h8*)(base + BM*32 + off);
        }
        #pragma unroll
        for (int j = 0; j < TN; ++j) {
            int row = (wn*TN + j)*16 + lrow;
            int off = row*32 + ((lq ^ sw)*8);
            bh[j] = *(const h8*)(base + PL*BM*32 + off);
            if (PL == 2) bl[j] = *(const h8*)(base + PL*BM*32 + BN*32 + off);
        }
        if constexpr (ASRC == 1) {
            if (i + 1 < steps) {
                // A-reg(next) are the oldest outstanding; B(next) stays in flight.
                __builtin_amdgcn_s_waitcnt(0x0F70 | NPW_B);
                stageA_write(sel ^ 1, arn);               // into next stage's A region
            }
        }
        if constexpr (MODE == 5) {
            if (i + 1 < steps) {
                // the W chunk was the FIRST of this iteration's NPW issues
                __builtin_amdgcn_s_waitcnt(0x0F70 | (NPW - 1));
                computeA(sel ^ 1, i + 1);                 // write A(next) into next stage
            }
        }
        #pragma unroll
        for (int i2 = 0; i2 < TM; ++i2)
            #pragma unroll
            for (int j = 0; j < TN; ++j)
                acc[i2][j] = __builtin_amdgcn_mfma_f32_16x16x32_f16(ah[i2], bh[j], acc[i2][j], 0, 0, 0);
        if (TERMS == 3) {
            #pragma unroll
            for (int i2 = 0; i2 < TM; ++i2)
                #pragma unroll
                for (int j = 0; j < TN; ++j)
                    acc[i2][j] = __builtin_amdgcn_mfma_f32_16x16x32_f16(ah[i2], bl[j], acc[i2][j], 0, 0, 0);
            #pragma unroll
            for (int i2 = 0; i2 < TM; ++i2)
                #pragma unroll
                for (int j = 0; j < TN; ++j)
                    acc[i2][j] = __builtin_amdgcn_mfma_f32_16x16x32_f16(al[i2], bh[j], acc[i2][j], 0, 0, 0);
        }
        if constexpr (MODE == 5 || ASRC == 1) {
            // publish this iteration's ds-written A(next) before the barrier
            asm volatile("s_waitcnt lgkmcnt(0)" ::: "memory");
        }
        __builtin_amdgcn_s_barrier();   // buffer consumed; next iter may prefetch into it
    }

    // ---- fused z-projection epilogue (MODE 4) ----
    if constexpr (MODE == 4) {
        static_assert(WN*16 == 32, "MODE 4 needs N2=32 across WN waves");
        static_assert(BM*BN <= STRIDE, "MODE 4 tile planes must fit smem");
        constexpr int PLANE = BM*BN;           // halves per plane
        constexpr int NC2 = BN/32;             // K2 chunks of 32
        constexpr int MF2 = TM;                // m-frags per wave (BM/(16*WM))
        const _Float16* Wh = (const _Float16*)Ch;
        const _Float16* Wl = (const _Float16*)Cl;
        _Float16* th = smem;
        _Float16* tl = smem + PLANE;

        // issue B2 (Wz^T chunk) loads early; independent of LDS
        const int n2 = wn*16 + lrow;           // 0..31
        h8 b2h[NC2], b2l[NC2];
        #pragma unroll
        for (int cc = 0; cc < NC2; ++cc) {
            size_t go = (size_t)n2*N + bn0 + cc*32 + lq*8;
            b2h[cc] = *(const h8*)(Wh + go);
            b2l[cc] = *(const h8*)(Wl + go);
        }

        // scatter bias+relu'd tile as hi/lo planes, layout [chunk][m][32] swizzled
        #pragma unroll
        for (int j = 0; j < TN; ++j) {
            int col = (wn*TN + j)*16 + lrow;   // k2 index 0..BN-1
            float bj = bias[bn0 + col];
            int c = col >> 5, kk = col & 31;
            #pragma unroll
            for (int i = 0; i < TM; ++i) {
                int m0 = (wm*TM + i)*16 + lq*4;
                #pragma unroll
                for (int r = 0; r < 4; ++r) {
                    float v = acc[i][j][r] + bj;
                    if (RELU) v = fmaxf(v, 0.0f);
                    int m = m0 + r;
                    int a = c*(BM*32) + m*32 + (((kk >> 3) ^ ((m >> 1) & 3))*8) + (kk & 7);
                    _Float16 hh = (_Float16)v;
                    th[a] = hh;
                    tl[a] = (_Float16)(v - (float)hh);
                }
            }
        }
        __syncthreads();

        f4 acc2[MF2];
        #pragma unroll
        for (int mf = 0; mf < MF2; ++mf) acc2[mf] = (f4)0.0f;
        #pragma unroll
        for (int mf = 0; mf < MF2; ++mf) {
            int mrow = (wm*TM + mf)*16 + lrow;
            #pragma unroll
            for (int cc = 0; cc < NC2; ++cc) {
                int off = cc*(BM*32) + mrow*32 + ((lq ^ sw)*8);
                h8 a2h = *(const h8*)(th + off);
                h8 a2l = *(const h8*)(tl + off);
                acc2[mf] = __builtin_amdgcn_mfma_f32_16x16x32_f16(a2h, b2h[cc], acc2[mf], 0, 0, 0);
                acc2[mf] = __builtin_amdgcn_mfma_f32_16x16x32_f16(a2h, b2l[cc], acc2[mf], 0, 0, 0);
                acc2[mf] = __builtin_amdgcn_mfma_f32_16x16x32_f16(a2l, b2h[cc], acc2[mf], 0, 0, 0);
            }
        }
        #pragma unroll
        for (int mf = 0; mf < MF2; ++mf) {
            int rb = bm0 + (wm*TM + mf)*16 + lq*4;
            #pragma unroll
            for (int r = 0; r < 4; ++r)
                atomicAdd(&Cf[(size_t)(rb + r)*32 + n2], acc2[mf][r]);
        }
        return;
    }

    // ---- epilogue ----
    float lsum = 0.0f;
    #pragma unroll
    for (int j = 0; j < TN; ++j) {
        int col = bn0 + (wn*TN + j)*16 + lrow;
        float bj = bias[col];
        #pragma unroll
        for (int i = 0; i < TM; ++i) {
            int rbase = bm0 + (wm*TM + i)*16 + lq*4;
            #pragma unroll
            for (int r = 0; r < 4; ++r) {
                float v = acc[i][j][r] + bj;
                if (RELU) v = fmaxf(v, 0.0f);
                size_t idx = (size_t)(rbase + r)*N + col;
                if (MODE == 2) {
                    float d = v - Xref[idx];
                    lsum = fmaf(d, d, lsum);
                } else if (MODE == 0) {
                    _Float16 hh = (_Float16)v;
                    __builtin_nontemporal_store(hh, &Ch[idx]);
                    __builtin_nontemporal_store((_Float16)(v - (float)hh), &Cl[idx]);
                } else if (MODE == 1) {
                    _Float16 hh = (_Float16)v;
                    __builtin_nontemporal_store(hh, &Ch[idx]);
                    __builtin_nontemporal_store(v, &Cf[idx]);
                } else {
                    __builtin_nontemporal_store((_Float16)v, &Ch[idx]);
                }
            }
        }
    }
    if (MODE == 2) {
        for (int off = 32; off > 0; off >>= 1) lsum += __shfl_down(lsum, off, 64);
        __syncthreads();
        float* sc = (float*)smem;
        if (lane == 0) sc[wave] = lsum;
        __syncthreads();
        if (tid == 0) {
            double t = 0.0;
            for (int w = 0; w < NW; ++w) t += (double)sc[w];
            atomicAdd(loss_acc, t);
        }
    }
}

// ---------------- block reduction helpers ----------------
__device__ __forceinline__ float blk_sum_f(float v, float* sh) {
    int tid = threadIdx.x;
    sh[tid] = v; __syncthreads();
    for (int s = 128; s > 0; s >>= 1) { if (tid < s) sh[tid] += sh[tid+s]; __syncthreads(); }
    float r = sh[0]; __syncthreads();
    return r;
}
__device__ __forceinline__ float blk_min_f(float v, float* sh) {
    int tid = threadIdx.x;
    sh[tid] = v; __syncthreads();
    for (int s = 128; s > 0; s >>= 1) { if (tid < s) sh[tid] = fminf(sh[tid], sh[tid+s]); __syncthreads(); }
    float r = sh[0]; __syncthreads();
    return r;
}

// ---------------- clustering pass: 4 threads per point (+ last-block finalize) ----------------
__global__ __launch_bounds__(256)
void cluster_pass(const float* __restrict__ z, const float* __restrict__ bz,
                  const float* __restrict__ t1,
                  const float* __restrict__ clusters,
                  float* __restrict__ D, float* __restrict__ ROWSUM,
                  float* __restrict__ pred_out, float* __restrict__ u_acc,
                  int* __restrict__ cnt, double* __restrict__ dbl,
                  float* __restrict__ f_out, int* __restrict__ blkctr)
{
    __shared__ __align__(16) float cl[KCL*33];
    __shared__ float u_s[KCL];
    __shared__ float swave[4];
    __shared__ float bzs[NZ_DIM];
    __shared__ int lastFlag;
    const int tid = threadIdx.x;
    const int lane = tid & 63;
    for (int i = tid; i < KCL*NZ_DIM; i += 256) cl[(i >> 5)*33 + (i & 31)] = clusters[i];
    if (tid < KCL) u_s[tid] = 0.0f;
    if (tid < NZ_DIM) bzs[tid] = bz[tid];
    __syncthreads();

    const int p  = (blockIdx.x*256 + tid) >> 2;
    const int kg = tid & 3;

    float zr[NZ_DIM];
    const float a = t1[p*3+0]*0.01f, b = t1[p*3+1]*0.01f, c = t1[p*3+2]*0.01f;
    const float cm = a*b*c*0.99f + 1.0f;
    float mean = 0.0f;
    #pragma unroll
    for (int i = 0; i < NZ_DIM; ++i) {
        zr[i] = (z[(size_t)p*NZ_DIM+i] + bzs[i])*cm;   // bias fold (was finish_z)
        mean += zr[i];
    }
    mean *= (1.0f/NZ_DIM);
    float var = 0.0f;
    #pragma unroll
    for (int i = 0; i < NZ_DIM; ++i) { float d = zr[i]-mean; var += d*d; }
    const float istd = 1.0f / sqrtf(var * (1.0f/(NZ_DIM-1)));
    #pragma unroll
    for (int i = 0; i < NZ_DIM; ++i) zr[i] = (zr[i]-mean)*istd;

    float vals[25];
    float rowsum = 0.0f, best = -1.0f; int bk = 0;
    #pragma unroll
    for (int j = 0; j < 25; ++j) {
        const int k = kg + 4*j;
        float d = 0.0f;
        #pragma unroll
        for (int i = 0; i < NZ_DIM; ++i) { float t = zr[i]-cl[k*33+i]; d = fmaf(t,t,d); }
        float val = 1e-5f + d;
        vals[j] = val;
        rowsum += val;
        if (val > best) { best = val; bk = k; }
        D[(size_t)p*KCL + k] = val;
    }
    rowsum += __shfl_xor(rowsum, 1);
    rowsum += __shfl_xor(rowsum, 2);
    #pragma unroll
    for (int m = 1; m <= 2; m <<= 1) {
        float ov = __shfl_xor(best, m);
        int   ok = __shfl_xor(bk, m);
        if (ov > best || (ov == best && ok < bk)) { best = ov; bk = ok; }
    }
    if (kg == 0) {
        pred_out[p] = (float)bk;
        atomicAdd(&cnt[bk], 1);
        ROWSUM[p] = rowsum;
    }

    const float inv_rs = 1.0f/rowsum;
    float Sp = 0.0f;
    #pragma unroll
    for (int j = 0; j < 25; ++j) {
        float qv = vals[j]*inv_rs;
        float lq = logf(qv);
        float om = 1.0f - qv;
        Sp += sqrtf(-1.0f/(om*om*lq*(float)M_PTS));
        float qs = qv;
        qs += __shfl_xor(qs, 4);
        qs += __shfl_xor(qs, 8);
        qs += __shfl_xor(qs, 16);
        qs += __shfl_xor(qs, 32);
        if (lane < 4) atomicAdd(&u_s[lane + 4*j], qs);
    }
    for (int off = 32; off > 0; off >>= 1) Sp += __shfl_down(Sp, off, 64);
    if (lane == 0) swave[tid >> 6] = Sp;
    __syncthreads();
    if (tid < KCL) atomicAdd(&u_acc[tid], u_s[tid]);
    if (tid == 0) atomicAdd(&dbl[0], (double)(swave[0]+swave[1]+swave[2]+swave[3]));

    // ---- last-block finalize (was finalize_kernel) ----
    __threadfence();
    __syncthreads();
    if (tid == 0) {
        int old = atomicAdd(blkctr, 1);
        lastFlag = (old == (int)gridDim.x - 1);
    }
    __syncthreads();
    if (!lastFlag) return;
    __threadfence();

    float* shF = cl;                         // reuse shared (13.2 KB >= 2 KB needed)
    double* shD = (double*)&cl[1024];        // 8B-aligned (cl is 16B-aligned)
    const bool act = (tid < KCL);
    const float S = (float)atomicAdd(&dbl[0], 0.0);   // coherent device-scope read

    float uv = act ? atomicAdd(&u_acc[tid], 0.0f) : 0.0f;
    float um = blk_sum_f(uv, shF) * (1.0f/KCL);
    float ud = act ? (uv - um) : 0.0f;
    float uvar = blk_sum_f(ud*ud, shF) * (1.0f/(KCL-1));
    float un = ud / sqrtf(uvar);
    float umin = blk_min_f(act ? un : 3.0e38f, shF);
    float ufin = un - umin + 0.001f;

    float vv = 0.0f;
    if (act) { int cc2 = atomicAdd(&cnt[tid], 0); if (cc2 < 1) cc2 = 1; vv = sqrtf((float)cc2) * S; }
    float vm = blk_sum_f(vv, shF) * (1.0f/KCL);
    float vd = act ? (vv - vm) : 0.0f;
    float vvar = blk_sum_f(vd*vd, shF) * (1.0f/(KCL-1));
    float vn = vd / sqrtf(vvar);
    float vmin = blk_min_f(act ? vn : 3.0e38f, shF);
    float vfin = vn - vmin + 0.001f;

    if (act) f_out[tid] = ufin + vfin + 1.0f;

    double dp = 0.0;
    for (int pair = tid; pair < KCL*KCL; pair += 256) {
        int i = pair / KCL, j = pair % KCL;
        float d = 0.0f;
        #pragma unroll
        for (int t2 = 0; t2 < NZ_DIM; ++t2) {
            float x = clusters[i*NZ_DIM+t2] - clusters[j*NZ_DIM+t2];
            d = fmaf(x, x, d);
        }
        dp += (double)d;
    }
    shD[tid] = dp; __syncthreads();
    for (int s = 128; s > 0; s >>= 1) { if (tid < s) shD[tid] += shD[tid+s]; __syncthreads(); }
    if (tid == 0) {
        dbl[3] = 0.01 * (double)(KCL*KCL - KCL) / shD[0];
    }
}

// ---------------- KL pass (+ last-block final loss) ----------------
__global__ __launch_bounds__(256)
void kl_pass(const float* __restrict__ D, const float* __restrict__ ROWSUM,
             const float* __restrict__ f, double* __restrict__ dbl,
             float* __restrict__ out, int* __restrict__ blkctr)
{
    __shared__ float fs[KCL], lfs[KCL];
    __shared__ float swave[4];
    __shared__ int lastFlag;
    const int tid = threadIdx.x;
    const int lane = tid & 63;
    if (tid < KCL) { float fv = f[tid]; fs[tid] = fv; lfs[tid] = logf(fv); }
    __syncthreads();

    const int p  = (blockIdx.x*256 + tid) >> 2;
    const int kg = tid & 3;

    float vals[25];
    #pragma unroll
    for (int j = 0; j < 25; ++j) vals[j] = D[(size_t)p*KCL + kg + 4*j];

    float sv = 0.0f;
    #pragma unroll
    for (int j = 0; j < 25; ++j) { float v = vals[j]; sv += v*v/fs[kg + 4*j]; }
    sv += __shfl_xor(sv, 1);
    sv += __shfl_xor(sv, 2);

    const float rowsum = ROWSUM[p];
    const float lrs = logf(rowsum), lsv = logf(sv);
    const float inv_sv = 1.0f/sv;
    float klp = 0.0f;
    #pragma unroll
    for (int j = 0; j < 25; ++j) {
        const int k = kg + 4*j;
        float v = vals[j];
        float pv = v*v/fs[k]*inv_sv;
        klp += pv*(logf(v) - lfs[k] - lsv + lrs);
    }
    for (int off = 32; off > 0; off >>= 1) klp += __shfl_down(klp, off, 64);
    if (lane == 0) swave[tid >> 6] = klp;
    __syncthreads();
    if (tid == 0) atomicAdd(&dbl[1], (double)(swave[0]+swave[1]+swave[2]+swave[3]));

    // ---- last-block final loss (was final_loss) ----
    __threadfence();
    __syncthreads();
    if (tid == 0) {
        int old = atomicAdd(blkctr, 1);
        lastFlag = (old == (int)gridDim.x - 1);
    }
    __syncthreads();
    if (!lastFlag) return;
    __threadfence();
    if (tid == 0) {
        double kl = atomicAdd(&dbl[1], 0.0) / (double)((size_t)M_PTS*KCL) * 0.01;
        double re = dbl[2] / (double)((size_t)M_PTS*1024);   // prior dispatch (xbar)
        out[0] = (float)(kl + re + dbl[3]);                  // dbl[3]: prior dispatch
    }
}

extern "C" void kernel_launch(void* const* d_in, const int* in_sizes, int n_in,
                              void* d_out, int out_size, void* d_ws, size_t ws_size,
                              hipStream_t stream)
{
    const float* x   = (const float*)d_in[0];
    const float* t1c = (const float*)d_in[1];
    const float* clu = (const float*)d_in[2];
    const float* We1 = (const float*)d_in[3];  const float* be1 = (const float*)d_in[4];
    const float* We2 = (const float*)d_in[5];  const float* be2 = (const float*)d_in[6];
    const float* We3 = (const float*)d_in[7];  const float* be3 = (const float*)d_in[8];
    const float* Wz  = (const float*)d_in[9];  const float* bz  = (const float*)d_in[10];
    const float* Wd1 = (const float*)d_in[11]; const float* bd1 = (const float*)d_in[12];
    const float* Wd2 = (const float*)d_in[13]; const float* bd2 = (const float*)d_in[14];
    const float* Wd3 = (const float*)d_in[15]; const float* bd3 = (const float*)d_in[16];
    const float* Wxb = (const float*)d_in[17]; const float* bxb = (const float*)d_in[18];
    float* out = (float*)d_out;

    const size_t M = M_PTS;
    _Float16* H = (_Float16*)d_ws;
    size_t o = 0;
    _Float16* BIGh = H + o; o += M*2048;   // unused by GEMMs now; kept for layout stability
    _Float16* BIGl = H + o; o += M*2048;   // unused; kept for layout stability
    _Float16* S1h  = H + o; o += M*512;    // h1 -> d2
    _Float16* S1l  = H + o; o += M*512;    // (dead after h3) -> D overlay
    _Float16* S2h  = H + o; o += M*512;    // h2 -> d3
    _Float16* S2l  = H + o; o += M*512;    // (dead after h3) -> ROWSUM overlay
    _Float16* Zh   = H + o; o += M*32;     // unused now; kept for layout stability
    _Float16* Zl   = H + o; o += M*32;     // unused; kept for layout stability
    _Float16* We1h = H + o; o += 512*1024; _Float16* We1l = H + o; o += 512*1024;
    _Float16* We2h = H + o; o += 512*512;  _Float16* We2l = H + o; o += 512*512;
    _Float16* We3h = H + o; o += 2048*512; _Float16* We3l = H + o; o += 2048*512;
    _Float16* Wzh  = H + o; o += 32*2048;  _Float16* Wzl  = H + o; o += 32*2048;
    _Float16* Wd1h = H + o; o += 2048*32;  _Float16* Wd1l = H + o; o += 2048*32;
    _Float16* Wd2h = H + o; o += 512*2048; _Float16* Wd2l = H + o; o += 512*2048;
    _Float16* Wd3h = H + o; o += 512*512;  _Float16* Wd3l = H + o; o += 512*512;
    _Float16* Wxbh = H + o; o += 1024*512; _Float16* Wxbl = H + o; o += 1024*512;
    float* fpr = (float*)(H + o);
    float* Zf  = fpr;        fpr += M*32;
    float* U   = fpr;        fpr += 128;
    float* F   = fpr;        fpr += 128;
    int*   CNT = (int*)fpr;  fpr += 128;
    double* DBL = (double*)(((uintptr_t)fpr + 15) & ~(uintptr_t)15);

    // last-block counters live in the CNT tail (zeroed by prep_weights)
    int* CTR_CL = CNT + 126;
    int* CTR_KL = CNT + 127;

    // D/ROWSUM overlay the dead encoder lo-planes (decoder never touches them)
    float* Dm  = (float*)S1l;
    float* RSm = (float*)S2l;

    // batched weight transpose+split (one launch) + folded zeroing of Zf/U/CNT/DBL
    {
        PrepW pa;
        const float* Ws[8]  = {We1, We2, We3, Wz, Wd1, Wd2, Wd3, Wxb};
        _Float16* Ths[8]    = {We1h, We2h, We3h, Wzh, Wd1h, Wd2h, Wd3h, Wxbh};
        _Float16* Tls[8]    = {We1l, We2l, We3l, Wzl, Wd1l, Wd2l, Wd3l, Wxbl};
        const int Ks[8]     = {1024, 512, 512, 2048, 32, 2048, 512, 512};
        const int Ns[8]     = {512, 512, 2048, 32, 2048, 512, 512, 1024};
        int acc = 0;
        for (int i = 0; i < 8; ++i) {
            pa.W[i] = Ws[i]; pa.Th[i] = Ths[i]; pa.Tl[i] = Tls[i];
            pa.K[i] = Ks[i]; pa.N[i] = Ns[i];
            pa.off[i] = acc;
            acc += (Ns[i] >> 5) * (Ks[i] >> 5);
        }
        pa.off[8] = acc;   // 3712
        prep_weights<<<acc, 256, 0, stream>>>(pa, Zf, U, CNT, DBL);
    }

    const int MB = M_PTS/128;  // 232
    // ---- encoder: f16x3 split precision (argmax-exact path) ----
    // L1: x split in-kernel (ASRC=1) — split_x dispatch eliminated
    gemm_sp<2,2,4,4,true ,0,3,1><<<dim3(4,  MB), 256, 0, stream>>>(nullptr, nullptr, We1h, We1l, be1, S1h, S1l, nullptr, x, nullptr, M, 512,  1024);
    gemm_sp<2,2,4,4,true ,0,3><<<dim3(4,  MB), 256, 0, stream>>>(S1h, S1l, We2h, We2l, be2, S2h, S2l, nullptr, nullptr, nullptr, M, 512,  512);
    // h3 GEMM with fused z-projection: no h3 materialization, z partials -> Zf atomics
    gemm_sp<2,2,4,4,true ,4,3><<<dim3(16, MB), 256, 0, stream>>>(S2h, S2l, We3h, We3l, be3, Wzh, Wzl, Zf, nullptr, nullptr, M, 2048, 512);
    // ---- decoder: plain f16 (feeds re_loss only) ----
    // d1 fused into d2 (MODE 5): A = relu((Zf+bz) @ Wd1 + bd1), z read as fp32+bias
    gemm_sp<2,2,4,4,true ,5,1><<<dim3(4,  MB), 256, 0, stream>>>((const _Float16*)Zf, Wd1h, Wd2h, nullptr, bd2, S1h, (_Float16*)bz, nullptr, bd1, nullptr, M, 512,  2048);
    gemm_sp<2,2,4,4,true ,3,1><<<dim3(4,  MB), 256, 0, stream>>>(S1h, nullptr, Wd3h, nullptr, bd3, S2h,  nullptr, nullptr, nullptr, nullptr, M, 512,  512);
    gemm_sp<2,2,4,4,false,2,1><<<dim3(8,  MB), 256, 0, stream>>>(S2h, nullptr, Wxbh, nullptr, bxb, nullptr, nullptr, nullptr, x, DBL+2, M, 1024, 512);

    const int PB = (M_PTS*4)/256;   // 464 blocks, 4 threads/point
    cluster_pass<<<PB, 256, 0, stream>>>(Zf, bz, t1c, clu, Dm, RSm, out, U, CNT, DBL, F, CTR_CL);
    kl_pass<<<PB, 256, 0, stream>>>(Dm, RSm, F, DBL, out + M_PTS, CTR_KL);
}

// Round 7
// 1068.988 us; speedup vs baseline: 1.1387x; 1.1387x over previous
//
#include <hip/hip_runtime.h>
#include <math.h>

#define M_PTS 29696
#define KCL 100
#define NZ_DIM 32

typedef _Float16 h8 __attribute__((ext_vector_type(8)));
typedef _Float16 h4 __attribute__((ext_vector_type(4)));
typedef float f4 __attribute__((ext_vector_type(4)));

// async global->LDS, 16B per lane; LDS dest is wave-uniform base + lane*16
__device__ __forceinline__ void load_lds16(const void* g, void* l) {
    __builtin_amdgcn_global_load_lds(
        (const __attribute__((address_space(1))) void*)g,
        (__attribute__((address_space(3))) void*)l, 16, 0, 0);
}

// ---------------- batched weight transpose+split (+ folded accumulator zeroing) ----------------
// W (KxN) fp32 -> WTh/WTl (NxK) f16 hi/lo planes, all 8 weights in one launch.
struct PrepW {
    const float* W[8];
    _Float16* Th[8];
    _Float16* Tl[8];
    int K[8];
    int N[8];
    int off[9];   // cumulative 32x32-tile counts, off[0]=0
};

__global__ __launch_bounds__(256)
void prep_weights(PrepW a, float* __restrict__ Zf, float* __restrict__ U,
                  int* __restrict__ CNT, double* __restrict__ DBL)
{
    __shared__ float t[32][33];
    const int bid = blockIdx.x;
    const int tid = threadIdx.x;

    // folded zeroing: first 928 blocks cover Zf (29696*32 floats) exactly
    if (bid < (M_PTS*NZ_DIM/4/256)) {
        const size_t zi = ((size_t)bid*256 + tid)*4;
        *(float4*)(Zf + zi) = make_float4(0.0f, 0.0f, 0.0f, 0.0f);
    }
    if (bid == 0) {
        if (tid < 128) { U[tid] = 0.0f; CNT[tid] = 0; }   // incl. last-block counters @126/127
        if (tid < 8) DBL[tid] = 0.0;
    }

    int w = 0;
    #pragma unroll
    for (int i = 1; i < 8; ++i) w += (bid >= a.off[i]);
    const int local = bid - a.off[w];
    const int K = a.K[w], N = a.N[w];
    const int tx = N >> 5;                       // tiles along N (power of 2)
    const int sh = __builtin_ctz(tx);
    const int n0 = (local & (tx - 1)) * 32, k0 = (local >> sh) * 32;
    const float* W = a.W[w];
    _Float16* WTh = a.Th[w];
    _Float16* WTl = a.Tl[w];

    {
        int r = tid / 8, c = (tid % 8) * 4;
        const float4 v = *(const float4*)(W + (size_t)(k0 + r) * N + n0 + c);
        t[r][c+0] = v.x; t[r][c+1] = v.y; t[r][c+2] = v.z; t[r][c+3] = v.w;
    }
    __syncthreads();
    {
        int r = tid / 8, c = (tid % 8) * 4;   // r = n idx, c = k idx
        h4 hi, lo;
        #pragma unroll
        for (int u = 0; u < 4; ++u) {
            float f = t[c+u][r];
            _Float16 h = (_Float16)f;
            hi[u] = h; lo[u] = (_Float16)(f - (float)h);
        }
        *(h4*)(WTh + (size_t)(n0 + r) * K + k0 + c) = hi;
        *(h4*)(WTl + (size_t)(n0 + r) * K + k0 + c) = lo;
    }
}

// ---------------- MFMA GEMM, async double-buffered LDS ----------------
// A planes: MxK f16; B planes: NxK f16. C = act(A@B^T + bias).
// TERMS=3: split-precision (hi*hi + hi*lo + lo*hi), PL=2 planes staged.
// TERMS=1: plain f16, PL=1.
// MODE 0: write hi+lo. MODE 1: hi + fp32. MODE 2: fused re-loss. MODE 3: hi only.
// MODE 4: no C write; fused z-projection: atomicAdd(Cf, relu(C+bias) @ Wz^T chunk),
//         with Ch/Cl reinterpreted as Wz^T hi/lo planes (32 x N layout, stride N).
// MODE 5: fused-A decoder: A = relu(Z @ Wd1 + bd1) computed in-kernel per K-step.
//         Ahp = Zf (Mx32 fp32, cast), Cl = bz (fp32, cast), Alp = Wd1h, Xref = bd1.
// ASRC 1: A staged from fp32 Xref (MxK), split hi/lo in-kernel (reg-staged,
//         T14 async split: load early, ds_write after barrier). Same LDS layout.
template<int WM,int WN,int TM,int TN,bool RELU,int MODE,int TERMS,int ASRC=0>
__global__ __launch_bounds__(WM*WN*64)
void gemm_sp(const _Float16* __restrict__ Ahp, const _Float16* __restrict__ Alp,
             const _Float16* __restrict__ Bhp, const _Float16* __restrict__ Blp,
             const float* __restrict__ bias,
             _Float16* __restrict__ Ch, _Float16* __restrict__ Cl,
             float* __restrict__ Cf, const float* __restrict__ Xref,
             double* __restrict__ loss_acc,
             int M, int N, int K)
{
    constexpr int BM = WM*TM*16, BN = WN*TN*16, NW = WM*WN;
    constexpr int PL = (TERMS == 3) ? 2 : 1;
    constexpr int CA = BM/16, CB = BN/16;          // 1KB chunks
    constexpr int STRIDE = PL*(BM+BN)*32;          // halves per stage
    // per-wave vmcnt-counted issues per stage (uniform across waves).
    // ASRC=1: the 4 A-reg float4 loads occupy the same count the A asyncs did.
    constexpr int NPW = ((MODE == 5) ? 1 : (CA/NW)*PL)
                      + ((CB >= NW) ? (CB/NW) : 1)*PL;
    constexpr int NPW_B = ((CB >= NW) ? (CB/NW) : 1)*PL;   // B-only in-flight bound
    static_assert(ASRC == 0 || (TERMS == 3 && (CA/NW) == 2 && MODE == 0),
                  "ASRC=1 path sized for the L1 config");
    // MODE5 extra LDS: wd1 chunk dbuf (2x1024 halves) + bd1 bias (2048 f32 = 4096 halves)
    constexpr int EXTRA = (MODE == 5) ? (2048 + 4096) : 0;
    __shared__ __align__(16) _Float16 smem[2*STRIDE + EXTRA];

    const int tid = threadIdx.x;
    const int wave = tid >> 6, lane = tid & 63;
    const int wm = wave / WN, wn = wave % WN;
    const int lrow = lane & 15, lq = lane >> 4;
    const int sw = (lrow >> 1) & 3;                // bank swizzle
    const int lr4 = lane >> 2, lc4 = lane & 3;     // staging row-in-chunk / 16B col
    const int bm0 = blockIdx.y * BM, bn0 = blockIdx.x * BN;

    f4 acc[TM][TN];
    #pragma unroll
    for (int i = 0; i < TM; ++i)
        #pragma unroll
        for (int j = 0; j < TN; ++j)
            acc[i][j] = (f4)0.0f;

    auto stage = [&](int s, int k0) {
        _Float16* base = smem + s*STRIDE;
        if constexpr (MODE == 5) {
            // Wd1 chunk for this K-step: 32 rows x 32 halves; per wave its wn-half (1KB).
            // Issued FIRST so the mid-loop vmcnt(NPW-1) guarantees its arrival.
            int r_in = lane >> 2;                        // 0..15
            int gk = (lane & 3) ^ ((r_in >> 1) & 3);     // same k-group swizzle as A staging
            load_lds16(Alp + (size_t)(k0 + wn*16 + r_in)*32 + gk*8,
                       smem + 2*STRIDE + s*1024 + wn*512);
        } else if constexpr (ASRC == 1) {
            // A staged via reg path (see stageA_*); nothing async here.
        } else {
            #pragma unroll
            for (int c = wave; c < CA; c += NW) {
                int r = c*16 + lr4;
                int g = lc4 ^ ((r >> 1) & 3);
                size_t goff = (size_t)(bm0 + r)*K + k0 + g*8;
                load_lds16(Ahp + goff, base + c*512);
                if (PL == 2) load_lds16(Alp + goff, base + BM*32 + c*512);
            }
        }
        if (CB >= NW) {
            #pragma unroll
            for (int c = wave; c < CB; c += NW) {
                int r = c*16 + lr4;
                int g = lc4 ^ ((r >> 1) & 3);
                size_t goff = (size_t)(bn0 + r)*K + k0 + g*8;
                load_lds16(Bhp + goff, base + PL*BM*32 + c*512);
                if (PL == 2) load_lds16(Blp + goff, base + PL*BM*32 + BN*32 + c*512);
            }
        } else {  // fewer B chunks than waves: duplicate issues keep counts uniform
            int c = wave % CB;
            int r = c*16 + lr4;
            int g = lc4 ^ ((r >> 1) & 3);
            size_t goff = (size_t)(bn0 + r)*K + k0 + g*8;
            load_lds16(Bhp + goff, base + PL*BM*32 + c*512);
            if (PL == 2) load_lds16(Blp + goff, base + PL*BM*32 + BN*32 + c*512);
        }
    };

    // ---- ASRC=1: fp32 A-split staging (reg-staged, async-split) ----
    auto stageA_load = [&](int k0, float4 (&ar)[4]) {
        if constexpr (ASRC == 1) {
            #pragma unroll
            for (int u = 0; u < 2; ++u) {              // chunks c = wave + u*NW
                int c = wave + u*NW;
                int r = c*16 + lr4;
                int g = lc4 ^ ((r >> 1) & 3);
                const float* src = Xref + (size_t)(bm0 + r)*K + k0 + g*8;
                ar[u*2+0] = *(const float4*)(src);
                ar[u*2+1] = *(const float4*)(src + 4);
            }
        }
    };
    auto stageA_write = [&](int s, const float4 (&ar)[4]) {
        if constexpr (ASRC == 1) {
            _Float16* base = smem + s*STRIDE;
            #pragma unroll
            for (int u = 0; u < 2; ++u) {
                int c = wave + u*NW;
                float fv[8] = {ar[u*2].x, ar[u*2].y, ar[u*2].z, ar[u*2].w,
                               ar[u*2+1].x, ar[u*2+1].y, ar[u*2+1].z, ar[u*2+1].w};
                h8 hi, lo;
                #pragma unroll
                for (int q = 0; q < 8; ++q) {
                    _Float16 h = (_Float16)fv[q];
                    hi[q] = h; lo[q] = (_Float16)(fv[q] - (float)h);
                }
                // identical layout to the async path: chunk base + lane*16B
                *(h8*)(base + c*512 + lane*8) = hi;
                *(h8*)(base + BM*32 + c*512 + lane*8) = lo;
            }
        }
    };

    // MODE5: z fragments (loop-invariant A rows of the inner d1 matmul), built from
    // fp32 Zf + bz (bitwise-identical to the old finish_z staged f16 plane).
    h8 zfr[(MODE == 5) ? TM : 1];
    auto computeA = [&](int ds, int s) {
        if constexpr (MODE == 5) {
            const _Float16* wslot = smem + 2*STRIDE + ds*1024 + wn*512;
            const float* bds = (const float*)(smem + 2*STRIDE + 2048);
            h8 wf = *(const h8*)(wslot + lrow*32 + ((lq ^ sw)*8));
            float bv = bds[s*32 + wn*16 + lrow];
            _Float16* areg = smem + ds*STRIDE;
            const int kc = wn*16 + lrow;               // d1-col within the 32-chunk
            #pragma unroll
            for (int i2 = 0; i2 < TM; ++i2) {
                f4 cc = __builtin_amdgcn_mfma_f32_16x16x32_f16(zfr[i2], wf, (f4)0.0f, 0, 0, 0);
                int cch = wm*TM + i2;
                #pragma unroll
                for (int r = 0; r < 4; ++r) {
                    float v = fmaxf(cc[r] + bv, 0.0f);
                    int r16 = lq*4 + r;
                    areg[cch*512 + r16*32 + (((kc >> 3) ^ ((r16 >> 1) & 3))*8) + (kc & 7)]
                        = (_Float16)v;
                }
            }
        }
    };

    float4 ar0[4];
    if constexpr (ASRC == 1) stageA_load(0, ar0);      // oldest vmcnt entries
    if constexpr (MODE == 5) {
        // stage bd1 -> LDS (2048 f32 = 8 chunks of 1KB), before stage(0,0)
        #pragma unroll
        for (int c = wave; c < 8; c += NW)
            load_lds16(Xref + c*256 + lane*4, smem + 2*STRIDE + 2048 + c*512);
        const float* zf32 = (const float*)Ahp;
        const float* bz32 = (const float*)Cl;
        float4 b0 = *(const float4*)(bz32 + lq*8);
        float4 b1 = *(const float4*)(bz32 + lq*8 + 4);
        float bb[8] = {b0.x,b0.y,b0.z,b0.w,b1.x,b1.y,b1.z,b1.w};
        #pragma unroll
        for (int i2 = 0; i2 < TM; ++i2) {
            const float* zsrc = zf32 + (size_t)(bm0 + (wm*TM + i2)*16 + lrow)*32 + lq*8;
            float4 z0 = *(const float4*)(zsrc);
            float4 z1 = *(const float4*)(zsrc + 4);
            float zz[8] = {z0.x,z0.y,z0.z,z0.w,z1.x,z1.y,z1.z,z1.w};
            #pragma unroll
            for (int q = 0; q < 8; ++q) zfr[i2][q] = (_Float16)(zz[q] + bb[q]);
        }
    }
    stage(0, 0);
    if constexpr (ASRC == 1) {
        __builtin_amdgcn_s_waitcnt(0x0F70 | NPW_B);    // A-reg(0) landed; B(0) may fly
        stageA_write(0, ar0);
        asm volatile("s_waitcnt lgkmcnt(0)" ::: "memory");  // publish before 1st barrier
    }
    if constexpr (MODE == 5) {
        __builtin_amdgcn_s_waitcnt(0x0F70);            // vmcnt(0): bias+W(0)+B(0) landed
        __builtin_amdgcn_s_barrier();
        computeA(0, 0);                                // A(0) into stage-0 A region
        asm volatile("s_waitcnt lgkmcnt(0)" ::: "memory");
        __builtin_amdgcn_s_barrier();                  // A(0) visible to all waves
    }

    const int steps = K >> 5;
    for (int i = 0; i < steps; ++i) {
        const int sel = i & 1;
        float4 arn[4];
        if (i + 1 < steps) {
            if constexpr (ASRC == 1) stageA_load((i + 1) << 5, arn);
            stage(sel ^ 1, (i + 1) << 5);                 // prefetch next stage
            __builtin_amdgcn_s_waitcnt(0x0F70 | NPW);     // drain current stage only
        } else {
            __builtin_amdgcn_s_waitcnt(0x0F70);
        }
        __builtin_amdgcn_s_barrier();                     // all waves' data visible

        const _Float16* base = smem + sel*STRIDE;
        h8 ah[TM], al[TM], bh[TN], bl[TN];
        #pragma unroll
        for (int i2 = 0; i2 < TM; ++i2) {
            int row = (wm*TM + i2)*16 + lrow;
            int off = row*32 + ((lq ^ sw)*8);
            ah[i2] = *(const h8*)(base + off);
            if (PL == 2) al[i2] = *(const h8*)(base + BM*32 + off);
        }
        #pragma unroll
        for (int j = 0; j < TN; ++j) {
            int row = (wn*TN + j)*16 + lrow;
            int off = row*32 + ((lq ^ sw)*8);
            bh[j] = *(const h8*)(base + PL*BM*32 + off);
            if (PL == 2) bl[j] = *(const h8*)(base + PL*BM*32 + BN*32 + off);
        }
        if constexpr (ASRC == 1) {
            if (i + 1 < steps) {
                // A-reg(next) are the oldest outstanding; B(next) stays in flight.
                __builtin_amdgcn_s_waitcnt(0x0F70 | NPW_B);
                stageA_write(sel ^ 1, arn);               // into next stage's A region
            }
        }
        if constexpr (MODE == 5) {
            if (i + 1 < steps) {
                // the W chunk was the FIRST of this iteration's NPW issues
                __builtin_amdgcn_s_waitcnt(0x0F70 | (NPW - 1));
                computeA(sel ^ 1, i + 1);                 // write A(next) into next stage
            }
        }
        #pragma unroll
        for (int i2 = 0; i2 < TM; ++i2)
            #pragma unroll
            for (int j = 0; j < TN; ++j)
                acc[i2][j] = __builtin_amdgcn_mfma_f32_16x16x32_f16(ah[i2], bh[j], acc[i2][j], 0, 0, 0);
        if (TERMS == 3) {
            #pragma unroll
            for (int i2 = 0; i2 < TM; ++i2)
                #pragma unroll
                for (int j = 0; j < TN; ++j)
                    acc[i2][j] = __builtin_amdgcn_mfma_f32_16x16x32_f16(ah[i2], bl[j], acc[i2][j], 0, 0, 0);
            #pragma unroll
            for (int i2 = 0; i2 < TM; ++i2)
                #pragma unroll
                for (int j = 0; j < TN; ++j)
                    acc[i2][j] = __builtin_amdgcn_mfma_f32_16x16x32_f16(al[i2], bh[j], acc[i2][j], 0, 0, 0);
        }
        if constexpr (MODE == 5 || ASRC == 1) {
            // publish this iteration's ds-written A(next) before the barrier
            asm volatile("s_waitcnt lgkmcnt(0)" ::: "memory");
        }
        __builtin_amdgcn_s_barrier();   // buffer consumed; next iter may prefetch into it
    }

    // ---- fused z-projection epilogue (MODE 4) ----
    if constexpr (MODE == 4) {
        static_assert(WN*16 == 32, "MODE 4 needs N2=32 across WN waves");
        static_assert(BM*BN <= STRIDE, "MODE 4 tile planes must fit smem");
        constexpr int PLANE = BM*BN;           // halves per plane
        constexpr int NC2 = BN/32;             // K2 chunks of 32
        constexpr int MF2 = TM;                // m-frags per wave (BM/(16*WM))
        const _Float16* Wh = (const _Float16*)Ch;
        const _Float16* Wl = (const _Float16*)Cl;
        _Float16* th = smem;
        _Float16* tl = smem + PLANE;

        // issue B2 (Wz^T chunk) loads early; independent of LDS
        const int n2 = wn*16 + lrow;           // 0..31
        h8 b2h[NC2], b2l[NC2];
        #pragma unroll
        for (int cc = 0; cc < NC2; ++cc) {
            size_t go = (size_t)n2*N + bn0 + cc*32 + lq*8;
            b2h[cc] = *(const h8*)(Wh + go);
            b2l[cc] = *(const h8*)(Wl + go);
        }

        // scatter bias+relu'd tile as hi/lo planes, layout [chunk][m][32] swizzled
        #pragma unroll
        for (int j = 0; j < TN; ++j) {
            int col = (wn*TN + j)*16 + lrow;   // k2 index 0..BN-1
            float bj = bias[bn0 + col];
            int c = col >> 5, kk = col & 31;
            #pragma unroll
            for (int i = 0; i < TM; ++i) {
                int m0 = (wm*TM + i)*16 + lq*4;
                #pragma unroll
                for (int r = 0; r < 4; ++r) {
                    float v = acc[i][j][r] + bj;
                    if (RELU) v = fmaxf(v, 0.0f);
                    int m = m0 + r;
                    int a = c*(BM*32) + m*32 + (((kk >> 3) ^ ((m >> 1) & 3))*8) + (kk & 7);
                    _Float16 hh = (_Float16)v;
                    th[a] = hh;
                    tl[a] = (_Float16)(v - (float)hh);
                }
            }
        }
        __syncthreads();

        f4 acc2[MF2];
        #pragma unroll
        for (int mf = 0; mf < MF2; ++mf) acc2[mf] = (f4)0.0f;
        #pragma unroll
        for (int mf = 0; mf < MF2; ++mf) {
            int mrow = (wm*TM + mf)*16 + lrow;
            #pragma unroll
            for (int cc = 0; cc < NC2; ++cc) {
                int off = cc*(BM*32) + mrow*32 + ((lq ^ sw)*8);
                h8 a2h = *(const h8*)(th + off);
                h8 a2l = *(const h8*)(tl + off);
                acc2[mf] = __builtin_amdgcn_mfma_f32_16x16x32_f16(a2h, b2h[cc], acc2[mf], 0, 0, 0);
                acc2[mf] = __builtin_amdgcn_mfma_f32_16x16x32_f16(a2h, b2l[cc], acc2[mf], 0, 0, 0);
                acc2[mf] = __builtin_amdgcn_mfma_f32_16x16x32_f16(a2l, b2h[cc], acc2[mf], 0, 0, 0);
            }
        }
        #pragma unroll
        for (int mf = 0; mf < MF2; ++mf) {
            int rb = bm0 + (wm*TM + mf)*16 + lq*4;
            #pragma unroll
            for (int r = 0; r < 4; ++r)
                atomicAdd(&Cf[(size_t)(rb + r)*32 + n2], acc2[mf][r]);
        }
        return;
    }

    // ---- epilogue ----
    float lsum = 0.0f;
    #pragma unroll
    for (int j = 0; j < TN; ++j) {
        int col = bn0 + (wn*TN + j)*16 + lrow;
        float bj = bias[col];
        #pragma unroll
        for (int i = 0; i < TM; ++i) {
            int rbase = bm0 + (wm*TM + i)*16 + lq*4;
            #pragma unroll
            for (int r = 0; r < 4; ++r) {
                float v = acc[i][j][r] + bj;
                if (RELU) v = fmaxf(v, 0.0f);
                size_t idx = (size_t)(rbase + r)*N + col;
                if (MODE == 2) {
                    float d = v - Xref[idx];
                    lsum = fmaf(d, d, lsum);
                } else if (MODE == 0) {
                    _Float16 hh = (_Float16)v;
                    __builtin_nontemporal_store(hh, &Ch[idx]);
                    __builtin_nontemporal_store((_Float16)(v - (float)hh), &Cl[idx]);
                } else if (MODE == 1) {
                    _Float16 hh = (_Float16)v;
                    __builtin_nontemporal_store(hh, &Ch[idx]);
                    __builtin_nontemporal_store(v, &Cf[idx]);
                } else {
                    __builtin_nontemporal_store((_Float16)v, &Ch[idx]);
                }
            }
        }
    }
    if (MODE == 2) {
        for (int off = 32; off > 0; off >>= 1) lsum += __shfl_down(lsum, off, 64);
        __syncthreads();
        float* sc = (float*)smem;
        if (lane == 0) sc[wave] = lsum;
        __syncthreads();
        if (tid == 0) {
            double t = 0.0;
            for (int w = 0; w < NW; ++w) t += (double)sc[w];
            atomicAdd(loss_acc, t);
        }
    }
}

// ---------------- block reduction helpers ----------------
__device__ __forceinline__ float blk_sum_f(float v, float* sh) {
    int tid = threadIdx.x;
    sh[tid] = v; __syncthreads();
    for (int s = 128; s > 0; s >>= 1) { if (tid < s) sh[tid] += sh[tid+s]; __syncthreads(); }
    float r = sh[0]; __syncthreads();
    return r;
}
__device__ __forceinline__ float blk_min_f(float v, float* sh) {
    int tid = threadIdx.x;
    sh[tid] = v; __syncthreads();
    for (int s = 128; s > 0; s >>= 1) { if (tid < s) sh[tid] = fminf(sh[tid], sh[tid+s]); __syncthreads(); }
    float r = sh[0]; __syncthreads();
    return r;
}

// ---------------- clustering pass: 4 threads per point (+ last-block finalize) ----------------
__global__ __launch_bounds__(256)
void cluster_pass(const float* __restrict__ z, const float* __restrict__ bz,
                  const float* __restrict__ t1,
                  const float* __restrict__ clusters,
                  float* __restrict__ D, float* __restrict__ ROWSUM,
                  float* __restrict__ pred_out, float* __restrict__ u_acc,
                  int* __restrict__ cnt, double* __restrict__ dbl,
                  float* __restrict__ f_out, int* __restrict__ blkctr)
{
    __shared__ __align__(16) float cl[KCL*33];
    __shared__ __align__(16) float Ds[64*KCL];    // D staging: 64 points x 100 k
    __shared__ float u_s[KCL];
    __shared__ float swave[4];
    __shared__ float bzs[NZ_DIM];
    __shared__ int lastFlag;
    const int tid = threadIdx.x;
    const int lane = tid & 63;
    for (int i = tid; i < KCL*NZ_DIM; i += 256) cl[(i >> 5)*33 + (i & 31)] = clusters[i];
    if (tid < KCL) u_s[tid] = 0.0f;
    if (tid < NZ_DIM) bzs[tid] = bz[tid];
    __syncthreads();

    const int p  = (blockIdx.x*256 + tid) >> 2;
    const int pl = tid >> 2;                      // point-in-block 0..63
    const int kg = tid & 3;

    float zr[NZ_DIM];
    const float a = t1[p*3+0]*0.01f, b = t1[p*3+1]*0.01f, c = t1[p*3+2]*0.01f;
    const float cm = a*b*c*0.99f + 1.0f;
    float mean = 0.0f;
    {   // vectorized z read (float4 x8), same accumulation order as scalar loop
        const float4* zv = (const float4*)(z + (size_t)p*NZ_DIM);
        #pragma unroll
        for (int u = 0; u < 8; ++u) {
            float4 v = zv[u];
            zr[u*4+0] = (v.x + bzs[u*4+0])*cm; mean += zr[u*4+0];
            zr[u*4+1] = (v.y + bzs[u*4+1])*cm; mean += zr[u*4+1];
            zr[u*4+2] = (v.z + bzs[u*4+2])*cm; mean += zr[u*4+2];
            zr[u*4+3] = (v.w + bzs[u*4+3])*cm; mean += zr[u*4+3];
        }
    }
    mean *= (1.0f/NZ_DIM);
    float var = 0.0f;
    #pragma unroll
    for (int i = 0; i < NZ_DIM; ++i) { float d = zr[i]-mean; var += d*d; }
    const float istd = 1.0f / sqrtf(var * (1.0f/(NZ_DIM-1)));
    #pragma unroll
    for (int i = 0; i < NZ_DIM; ++i) zr[i] = (zr[i]-mean)*istd;

    float vals[25];
    float rowsum = 0.0f, best = -1.0f; int bk = 0;
    #pragma unroll
    for (int j = 0; j < 25; ++j) {
        const int k = kg + 4*j;
        float d = 0.0f;
        #pragma unroll
        for (int i = 0; i < NZ_DIM; ++i) { float t = zr[i]-cl[k*33+i]; d = fmaf(t,t,d); }
        float val = 1e-5f + d;
        vals[j] = val;
        rowsum += val;
        if (val > best) { best = val; bk = k; }
        Ds[pl*KCL + k] = val;                     // stage to LDS (coalesced flush later)
    }
    rowsum += __shfl_xor(rowsum, 1);
    rowsum += __shfl_xor(rowsum, 2);
    #pragma unroll
    for (int m = 1; m <= 2; m <<= 1) {
        float ov = __shfl_xor(best, m);
        int   ok = __shfl_xor(bk, m);
        if (ov > best || (ov == best && ok < bk)) { best = ov; bk = ok; }
    }
    if (kg == 0) {
        pred_out[p] = (float)bk;
        atomicAdd(&cnt[bk], 1);
        ROWSUM[p] = rowsum;
    }

    // coalesced D flush: block's 64x100 slab as float4
    __syncthreads();
    {
        float4* dst = (float4*)(D + (size_t)blockIdx.x * (64*KCL));
        const float4* src = (const float4*)Ds;
        for (int q = tid; q < (64*KCL)/4; q += 256) dst[q] = src[q];
    }

    const float inv_rs = 1.0f/rowsum;
    float Sp = 0.0f;
    #pragma unroll
    for (int j = 0; j < 25; ++j) {
        float qv = vals[j]*inv_rs;
        float lq = logf(qv);
        float om = 1.0f - qv;
        Sp += sqrtf(-1.0f/(om*om*lq*(float)M_PTS));
        float qs = qv;
        qs += __shfl_xor(qs, 4);
        qs += __shfl_xor(qs, 8);
        qs += __shfl_xor(qs, 16);
        qs += __shfl_xor(qs, 32);
        if (lane < 4) atomicAdd(&u_s[lane + 4*j], qs);
    }
    for (int off = 32; off > 0; off >>= 1) Sp += __shfl_down(Sp, off, 64);
    if (lane == 0) swave[tid >> 6] = Sp;
    __syncthreads();
    if (tid < KCL) atomicAdd(&u_acc[tid], u_s[tid]);
    if (tid == 0) atomicAdd(&dbl[0], (double)(swave[0]+swave[1]+swave[2]+swave[3]));

    // ---- last-block finalize (was finalize_kernel) ----
    // NOTE: no __threadfence() — on multi-XCD gfx950 it forces an L2 wb/inv per
    // block (catastrophic). All cross-block data flows via device-scope atomics;
    // __syncthreads() drains vmcnt(0) for every thread before tid0 signals.
    __syncthreads();
    if (tid == 0) {
        int old = atomicAdd(blkctr, 1);
        lastFlag = (old == (int)gridDim.x - 1);
    }
    __syncthreads();
    if (!lastFlag) return;

    float* shF = cl;                         // reuse shared (13.2 KB >= 2 KB needed)
    double* shD = (double*)&cl[1024];        // 8B-aligned (cl is 16B-aligned)
    const bool act = (tid < KCL);
    const float S = (float)atomicAdd(&dbl[0], 0.0);   // coherent device-scope read

    float uv = act ? atomicAdd(&u_acc[tid], 0.0f) : 0.0f;
    float um = blk_sum_f(uv, shF) * (1.0f/KCL);
    float ud = act ? (uv - um) : 0.0f;
    float uvar = blk_sum_f(ud*ud, shF) * (1.0f/(KCL-1));
    float un = ud / sqrtf(uvar);
    float umin = blk_min_f(act ? un : 3.0e38f, shF);
    float ufin = un - umin + 0.001f;

    float vv = 0.0f;
    if (act) { int cc2 = atomicAdd(&cnt[tid], 0); if (cc2 < 1) cc2 = 1; vv = sqrtf((float)cc2) * S; }
    float vm = blk_sum_f(vv, shF) * (1.0f/KCL);
    float vd = act ? (vv - vm) : 0.0f;
    float vvar = blk_sum_f(vd*vd, shF) * (1.0f/(KCL-1));
    float vn = vd / sqrtf(vvar);
    float vmin = blk_min_f(act ? vn : 3.0e38f, shF);
    float vfin = vn - vmin + 0.001f;

    if (act) f_out[tid] = ufin + vfin + 1.0f;

    double dp = 0.0;
    for (int pair = tid; pair < KCL*KCL; pair += 256) {
        int i = pair / KCL, j = pair % KCL;
        float d = 0.0f;
        #pragma unroll
        for (int t2 = 0; t2 < NZ_DIM; ++t2) {
            float x = clusters[i*NZ_DIM+t2] - clusters[j*NZ_DIM+t2];
            d = fmaf(x, x, d);
        }
        dp += (double)d;
    }
    shD[tid] = dp; __syncthreads();
    for (int s = 128; s > 0; s >>= 1) { if (tid < s) shD[tid] += shD[tid+s]; __syncthreads(); }
    if (tid == 0) {
        dbl[3] = 0.01 * (double)(KCL*KCL - KCL) / shD[0];
    }
}

// ---------------- KL pass (+ last-block final loss) ----------------
__global__ __launch_bounds__(256)
void kl_pass(const float* __restrict__ D, const float* __restrict__ ROWSUM,
             const float* __restrict__ f, double* __restrict__ dbl,
             float* __restrict__ out, int* __restrict__ blkctr)
{
    __shared__ __align__(16) float Ds[64*KCL];
    __shared__ float fs[KCL], lfs[KCL];
    __shared__ float swave[4];
    __shared__ int lastFlag;
    const int tid = threadIdx.x;
    const int lane = tid & 63;
    // coalesced stage of this block's D slab
    {
        const float4* src = (const float4*)(D + (size_t)blockIdx.x * (64*KCL));
        float4* dst = (float4*)Ds;
        for (int q = tid; q < (64*KCL)/4; q += 256) dst[q] = src[q];
    }
    if (tid < KCL) { float fv = f[tid]; fs[tid] = fv; lfs[tid] = logf(fv); }
    __syncthreads();

    const int p  = (blockIdx.x*256 + tid) >> 2;
    const int pl = tid >> 2;
    const int kg = tid & 3;

    float vals[25];
    #pragma unroll
    for (int j = 0; j < 25; ++j) vals[j] = Ds[pl*KCL + kg + 4*j];

    float sv = 0.0f;
    #pragma unroll
    for (int j = 0; j < 25; ++j) { float v = vals[j]; sv += v*v/fs[kg + 4*j]; }
    sv += __shfl_xor(sv, 1);
    sv += __shfl_xor(sv, 2);

    const float rowsum = ROWSUM[p];
    const float lrs = logf(rowsum), lsv = logf(sv);
    const float inv_sv = 1.0f/sv;
    float klp = 0.0f;
    #pragma unroll
    for (int j = 0; j < 25; ++j) {
        const int k = kg + 4*j;
        float v = vals[j];
        float pv = v*v/fs[k]*inv_sv;
        klp += pv*(logf(v) - lfs[k] - lsv + lrs);
    }
    for (int off = 32; off > 0; off >>= 1) klp += __shfl_down(klp, off, 64);
    if (lane == 0) swave[tid >> 6] = klp;
    __syncthreads();
    if (tid == 0) atomicAdd(&dbl[1], (double)(swave[0]+swave[1]+swave[2]+swave[3]));

    // ---- last-block final loss (no threadfence; see cluster_pass note) ----
    __syncthreads();
    if (tid == 0) {
        int old = atomicAdd(blkctr, 1);
        lastFlag = (old == (int)gridDim.x - 1);
    }
    __syncthreads();
    if (!lastFlag) return;
    if (tid == 0) {
        double kl = atomicAdd(&dbl[1], 0.0) / (double)((size_t)M_PTS*KCL) * 0.01;
        double re = dbl[2] / (double)((size_t)M_PTS*1024);   // prior dispatch (xbar)
        out[0] = (float)(kl + re + dbl[3]);                  // dbl[3]: prior dispatch
    }
}

extern "C" void kernel_launch(void* const* d_in, const int* in_sizes, int n_in,
                              void* d_out, int out_size, void* d_ws, size_t ws_size,
                              hipStream_t stream)
{
    const float* x   = (const float*)d_in[0];
    const float* t1c = (const float*)d_in[1];
    const float* clu = (const float*)d_in[2];
    const float* We1 = (const float*)d_in[3];  const float* be1 = (const float*)d_in[4];
    const float* We2 = (const float*)d_in[5];  const float* be2 = (const float*)d_in[6];
    const float* We3 = (const float*)d_in[7];  const float* be3 = (const float*)d_in[8];
    const float* Wz  = (const float*)d_in[9];  const float* bz  = (const float*)d_in[10];
    const float* Wd1 = (const float*)d_in[11]; const float* bd1 = (const float*)d_in[12];
    const float* Wd2 = (const float*)d_in[13]; const float* bd2 = (const float*)d_in[14];
    const float* Wd3 = (const float*)d_in[15]; const float* bd3 = (const float*)d_in[16];
    const float* Wxb = (const float*)d_in[17]; const float* bxb = (const float*)d_in[18];
    float* out = (float*)d_out;

    const size_t M = M_PTS;
    _Float16* H = (_Float16*)d_ws;
    size_t o = 0;
    _Float16* BIGh = H + o; o += M*2048;   // unused by GEMMs now; kept for layout stability
    _Float16* BIGl = H + o; o += M*2048;   // unused; kept for layout stability
    _Float16* S1h  = H + o; o += M*512;    // h1 -> d2
    _Float16* S1l  = H + o; o += M*512;    // (dead after h3) -> D overlay
    _Float16* S2h  = H + o; o += M*512;    // h2 -> d3
    _Float16* S2l  = H + o; o += M*512;    // (dead after h3) -> ROWSUM overlay
    _Float16* Zh   = H + o; o += M*32;     // unused now; kept for layout stability
    _Float16* Zl   = H + o; o += M*32;     // unused; kept for layout stability
    _Float16* We1h = H + o; o += 512*1024; _Float16* We1l = H + o; o += 512*1024;
    _Float16* We2h = H + o; o += 512*512;  _Float16* We2l = H + o; o += 512*512;
    _Float16* We3h = H + o; o += 2048*512; _Float16* We3l = H + o; o += 2048*512;
    _Float16* Wzh  = H + o; o += 32*2048;  _Float16* Wzl  = H + o; o += 32*2048;
    _Float16* Wd1h = H + o; o += 2048*32;  _Float16* Wd1l = H + o; o += 2048*32;
    _Float16* Wd2h = H + o; o += 512*2048; _Float16* Wd2l = H + o; o += 512*2048;
    _Float16* Wd3h = H + o; o += 512*512;  _Float16* Wd3l = H + o; o += 512*512;
    _Float16* Wxbh = H + o; o += 1024*512; _Float16* Wxbl = H + o; o += 1024*512;
    float* fpr = (float*)(H + o);
    float* Zf  = fpr;        fpr += M*32;
    float* U   = fpr;        fpr += 128;
    float* F   = fpr;        fpr += 128;
    int*   CNT = (int*)fpr;  fpr += 128;
    double* DBL = (double*)(((uintptr_t)fpr + 15) & ~(uintptr_t)15);

    // last-block counters live in the CNT tail (zeroed by prep_weights)
    int* CTR_CL = CNT + 126;
    int* CTR_KL = CNT + 127;

    // D/ROWSUM overlay the dead encoder lo-planes (decoder never touches them)
    float* Dm  = (float*)S1l;
    float* RSm = (float*)S2l;

    // batched weight transpose+split (one launch) + folded zeroing of Zf/U/CNT/DBL
    {
        PrepW pa;
        const float* Ws[8]  = {We1, We2, We3, Wz, Wd1, Wd2, Wd3, Wxb};
        _Float16* Ths[8]    = {We1h, We2h, We3h, Wzh, Wd1h, Wd2h, Wd3h, Wxbh};
        _Float16* Tls[8]    = {We1l, We2l, We3l, Wzl, Wd1l, Wd2l, Wd3l, Wxbl};
        const int Ks[8]     = {1024, 512, 512, 2048, 32, 2048, 512, 512};
        const int Ns[8]     = {512, 512, 2048, 32, 2048, 512, 512, 1024};
        int acc = 0;
        for (int i = 0; i < 8; ++i) {
            pa.W[i] = Ws[i]; pa.Th[i] = Ths[i]; pa.Tl[i] = Tls[i];
            pa.K[i] = Ks[i]; pa.N[i] = Ns[i];
            pa.off[i] = acc;
            acc += (Ns[i] >> 5) * (Ks[i] >> 5);
        }
        pa.off[8] = acc;   // 3712
        prep_weights<<<acc, 256, 0, stream>>>(pa, Zf, U, CNT, DBL);
    }

    const int MB = M_PTS/128;  // 232
    // ---- encoder: f16x3 split precision (argmax-exact path) ----
    // L1: x split in-kernel (ASRC=1) — split_x dispatch eliminated
    gemm_sp<2,2,4,4,true ,0,3,1><<<dim3(4,  MB), 256, 0, stream>>>(nullptr, nullptr, We1h, We1l, be1, S1h, S1l, nullptr, x, nullptr, M, 512,  1024);
    gemm_sp<2,2,4,4,true ,0,3><<<dim3(4,  MB), 256, 0, stream>>>(S1h, S1l, We2h, We2l, be2, S2h, S2l, nullptr, nullptr, nullptr, M, 512,  512);
    // h3 GEMM with fused z-projection: no h3 materialization, z partials -> Zf atomics
    gemm_sp<2,2,4,4,true ,4,3><<<dim3(16, MB), 256, 0, stream>>>(S2h, S2l, We3h, We3l, be3, Wzh, Wzl, Zf, nullptr, nullptr, M, 2048, 512);
    // ---- decoder: plain f16 (feeds re_loss only) ----
    // d1 fused into d2 (MODE 5): A = relu((Zf+bz) @ Wd1 + bd1), z read as fp32+bias
    gemm_sp<2,2,4,4,true ,5,1><<<dim3(4,  MB), 256, 0, stream>>>((const _Float16*)Zf, Wd1h, Wd2h, nullptr, bd2, S1h, (_Float16*)bz, nullptr, bd1, nullptr, M, 512,  2048);
    gemm_sp<2,2,4,4,true ,3,1><<<dim3(4,  MB), 256, 0, stream>>>(S1h, nullptr, Wd3h, nullptr, bd3, S2h,  nullptr, nullptr, nullptr, nullptr, M, 512,  512);
    gemm_sp<2,2,4,4,false,2,1><<<dim3(8,  MB), 256, 0, stream>>>(S2h, nullptr, Wxbh, nullptr, bxb, nullptr, nullptr, nullptr, x, DBL+2, M, 1024, 512);

    const int PB = (M_PTS*4)/256;   // 464 blocks, 4 threads/point
    cluster_pass<<<PB, 256, 0, stream>>>(Zf, bz, t1c, clu, Dm, RSm, out, U, CNT, DBL, F, CTR_CL);
    kl_pass<<<PB, 256, 0, stream>>>(Dm, RSm, F, DBL, out + M_PTS, CTR_KL);
}

// Round 8
// 1054.683 us; speedup vs baseline: 1.1541x; 1.0136x over previous
//
#include <hip/hip_runtime.h>
#include <math.h>

#define M_PTS 29696
#define KCL 100
#define NZ_DIM 32

typedef _Float16 h8 __attribute__((ext_vector_type(8)));
typedef _Float16 h4 __attribute__((ext_vector_type(4)));
typedef float f4 __attribute__((ext_vector_type(4)));

// async global->LDS, 16B per lane; LDS dest is wave-uniform base + lane*16
__device__ __forceinline__ void load_lds16(const void* g, void* l) {
    __builtin_amdgcn_global_load_lds(
        (const __attribute__((address_space(1))) void*)g,
        (__attribute__((address_space(3))) void*)l, 16, 0, 0);
}

// ---------------- batched weight transpose+split (+ folded accumulator zeroing) ----------------
// W (KxN) fp32 -> WTh/WTl (NxK) f16 hi/lo planes, all 8 weights in one launch.
struct PrepW {
    const float* W[8];
    _Float16* Th[8];
    _Float16* Tl[8];
    int K[8];
    int N[8];
    int off[9];   // cumulative 32x32-tile counts, off[0]=0
};

__global__ __launch_bounds__(256)
void prep_weights(PrepW a, float* __restrict__ Zf, float* __restrict__ U,
                  int* __restrict__ CNT, double* __restrict__ DBL)
{
    __shared__ float t[32][33];
    const int bid = blockIdx.x;
    const int tid = threadIdx.x;

    // folded zeroing: first 928 blocks cover Zf (29696*32 floats) exactly
    if (bid < (M_PTS*NZ_DIM/4/256)) {
        const size_t zi = ((size_t)bid*256 + tid)*4;
        *(float4*)(Zf + zi) = make_float4(0.0f, 0.0f, 0.0f, 0.0f);
    }
    if (bid == 0) {
        if (tid < 128) { U[tid] = 0.0f; CNT[tid] = 0; }   // incl. last-block counters @126/127
        if (tid < 8) DBL[tid] = 0.0;
    }

    int w = 0;
    #pragma unroll
    for (int i = 1; i < 8; ++i) w += (bid >= a.off[i]);
    const int local = bid - a.off[w];
    const int K = a.K[w], N = a.N[w];
    const int tx = N >> 5;                       // tiles along N (power of 2)
    const int sh = __builtin_ctz(tx);
    const int n0 = (local & (tx - 1)) * 32, k0 = (local >> sh) * 32;
    const float* W = a.W[w];
    _Float16* WTh = a.Th[w];
    _Float16* WTl = a.Tl[w];

    {
        int r = tid / 8, c = (tid % 8) * 4;
        const float4 v = *(const float4*)(W + (size_t)(k0 + r) * N + n0 + c);
        t[r][c+0] = v.x; t[r][c+1] = v.y; t[r][c+2] = v.z; t[r][c+3] = v.w;
    }
    __syncthreads();
    {
        int r = tid / 8, c = (tid % 8) * 4;   // r = n idx, c = k idx
        h4 hi, lo;
        #pragma unroll
        for (int u = 0; u < 4; ++u) {
            float f = t[c+u][r];
            _Float16 h = (_Float16)f;
            hi[u] = h; lo[u] = (_Float16)(f - (float)h);
        }
        *(h4*)(WTh + (size_t)(n0 + r) * K + k0 + c) = hi;
        *(h4*)(WTl + (size_t)(n0 + r) * K + k0 + c) = lo;
    }
}

// ---------------- MFMA GEMM, async double-buffered LDS ----------------
// A planes: MxK f16; B planes: NxK f16. C = act(A@B^T + bias).
// TERMS=3: split-precision (hi*hi + hi*lo + lo*hi), PL=2 planes staged.
// TERMS=1: plain f16, PL=1.
// MODE 0: write hi+lo. MODE 1: hi + fp32. MODE 2: fused re-loss. MODE 3: hi only.
// MODE 4: no C write; fused z-projection: atomicAdd(Cf, relu(C+bias) @ Wz^T chunk),
//         with Ch/Cl reinterpreted as Wz^T hi/lo planes (32 x N layout, stride N).
// MODE 5: fused-A decoder: A = relu(Z @ Wd1 + bd1) computed in-kernel per K-step.
//         Ahp = Zf (Mx32 fp32, cast), Cl = bz (fp32, cast), Alp = Wd1h, Xref = bd1.
// ASRC 1: A staged from fp32 Xref (MxK), split hi/lo in-kernel (reg-staged,
//         T14 async split: load early, ds_write after barrier). Same LDS layout.
template<int WM,int WN,int TM,int TN,bool RELU,int MODE,int TERMS,int ASRC=0>
__global__ __launch_bounds__(WM*WN*64)
void gemm_sp(const _Float16* __restrict__ Ahp, const _Float16* __restrict__ Alp,
             const _Float16* __restrict__ Bhp, const _Float16* __restrict__ Blp,
             const float* __restrict__ bias,
             _Float16* __restrict__ Ch, _Float16* __restrict__ Cl,
             float* __restrict__ Cf, const float* __restrict__ Xref,
             double* __restrict__ loss_acc,
             int M, int N, int K)
{
    constexpr int BM = WM*TM*16, BN = WN*TN*16, NW = WM*WN;
    constexpr int PL = (TERMS == 3) ? 2 : 1;
    constexpr int CA = BM/16, CB = BN/16;          // 1KB chunks
    constexpr int STRIDE = PL*(BM+BN)*32;          // halves per stage
    // per-wave vmcnt-counted issues per stage (uniform across waves).
    // ASRC=1: the 4 A-reg float4 loads occupy the same count the A asyncs did.
    constexpr int NPW = ((MODE == 5) ? 1 : (CA/NW)*PL)
                      + ((CB >= NW) ? (CB/NW) : 1)*PL;
    constexpr int NPW_B = ((CB >= NW) ? (CB/NW) : 1)*PL;   // B-only in-flight bound
    static_assert(ASRC == 0 || (TERMS == 3 && (CA/NW) == 2 && MODE == 0),
                  "ASRC=1 path sized for the L1 config");
    // MODE5 extra LDS: wd1 chunk dbuf (2x1024 halves) + bd1 bias (2048 f32 = 4096 halves)
    constexpr int EXTRA = (MODE == 5) ? (2048 + 4096) : 0;
    __shared__ __align__(16) _Float16 smem[2*STRIDE + EXTRA];

    const int tid = threadIdx.x;
    const int wave = tid >> 6, lane = tid & 63;
    const int wm = wave / WN, wn = wave % WN;
    const int lrow = lane & 15, lq = lane >> 4;
    const int sw = (lrow >> 1) & 3;                // bank swizzle
    const int lr4 = lane >> 2, lc4 = lane & 3;     // staging row-in-chunk / 16B col
    const int bm0 = blockIdx.y * BM, bn0 = blockIdx.x * BN;

    f4 acc[TM][TN];
    #pragma unroll
    for (int i = 0; i < TM; ++i)
        #pragma unroll
        for (int j = 0; j < TN; ++j)
            acc[i][j] = (f4)0.0f;

    auto stage = [&](int s, int k0) {
        _Float16* base = smem + s*STRIDE;
        if constexpr (MODE == 5) {
            // Wd1 chunk for this K-step: 32 rows x 32 halves; per wave its wn-half (1KB).
            // Issued FIRST so the mid-loop vmcnt(NPW-1) guarantees its arrival.
            int r_in = lane >> 2;                        // 0..15
            int gk = (lane & 3) ^ ((r_in >> 1) & 3);     // same k-group swizzle as A staging
            load_lds16(Alp + (size_t)(k0 + wn*16 + r_in)*32 + gk*8,
                       smem + 2*STRIDE + s*1024 + wn*512);
        } else if constexpr (ASRC == 1) {
            // A staged via reg path (see stageA_*); nothing async here.
        } else {
            #pragma unroll
            for (int c = wave; c < CA; c += NW) {
                int r = c*16 + lr4;
                int g = lc4 ^ ((r >> 1) & 3);
                size_t goff = (size_t)(bm0 + r)*K + k0 + g*8;
                load_lds16(Ahp + goff, base + c*512);
                if (PL == 2) load_lds16(Alp + goff, base + BM*32 + c*512);
            }
        }
        if (CB >= NW) {
            #pragma unroll
            for (int c = wave; c < CB; c += NW) {
                int r = c*16 + lr4;
                int g = lc4 ^ ((r >> 1) & 3);
                size_t goff = (size_t)(bn0 + r)*K + k0 + g*8;
                load_lds16(Bhp + goff, base + PL*BM*32 + c*512);
                if (PL == 2) load_lds16(Blp + goff, base + PL*BM*32 + BN*32 + c*512);
            }
        } else {  // fewer B chunks than waves: duplicate issues keep counts uniform
            int c = wave % CB;
            int r = c*16 + lr4;
            int g = lc4 ^ ((r >> 1) & 3);
            size_t goff = (size_t)(bn0 + r)*K + k0 + g*8;
            load_lds16(Bhp + goff, base + PL*BM*32 + c*512);
            if (PL == 2) load_lds16(Blp + goff, base + PL*BM*32 + BN*32 + c*512);
        }
    };

    // ---- ASRC=1: fp32 A-split staging (reg-staged, async-split) ----
    auto stageA_load = [&](int k0, float4 (&ar)[4]) {
        if constexpr (ASRC == 1) {
            #pragma unroll
            for (int u = 0; u < 2; ++u) {              // chunks c = wave + u*NW
                int c = wave + u*NW;
                int r = c*16 + lr4;
                int g = lc4 ^ ((r >> 1) & 3);
                const float* src = Xref + (size_t)(bm0 + r)*K + k0 + g*8;
                ar[u*2+0] = *(const float4*)(src);
                ar[u*2+1] = *(const float4*)(src + 4);
            }
        }
    };
    auto stageA_write = [&](int s, const float4 (&ar)[4]) {
        if constexpr (ASRC == 1) {
            _Float16* base = smem + s*STRIDE;
            #pragma unroll
            for (int u = 0; u < 2; ++u) {
                int c = wave + u*NW;
                float fv[8] = {ar[u*2].x, ar[u*2].y, ar[u*2].z, ar[u*2].w,
                               ar[u*2+1].x, ar[u*2+1].y, ar[u*2+1].z, ar[u*2+1].w};
                h8 hi, lo;
                #pragma unroll
                for (int q = 0; q < 8; ++q) {
                    _Float16 h = (_Float16)fv[q];
                    hi[q] = h; lo[q] = (_Float16)(fv[q] - (float)h);
                }
                // identical layout to the async path: chunk base + lane*16B
                *(h8*)(base + c*512 + lane*8) = hi;
                *(h8*)(base + BM*32 + c*512 + lane*8) = lo;
            }
        }
    };

    // MODE5: z fragments (loop-invariant A rows of the inner d1 matmul), built from
    // fp32 Zf + bz (bitwise-identical to the old finish_z staged f16 plane).
    h8 zfr[(MODE == 5) ? TM : 1];
    auto computeA = [&](int ds, int s) {
        if constexpr (MODE == 5) {
            const _Float16* wslot = smem + 2*STRIDE + ds*1024 + wn*512;
            const float* bds = (const float*)(smem + 2*STRIDE + 2048);
            h8 wf = *(const h8*)(wslot + lrow*32 + ((lq ^ sw)*8));
            float bv = bds[s*32 + wn*16 + lrow];
            _Float16* areg = smem + ds*STRIDE;
            const int kc = wn*16 + lrow;               // d1-col within the 32-chunk
            #pragma unroll
            for (int i2 = 0; i2 < TM; ++i2) {
                f4 cc = __builtin_amdgcn_mfma_f32_16x16x32_f16(zfr[i2], wf, (f4)0.0f, 0, 0, 0);
                int cch = wm*TM + i2;
                #pragma unroll
                for (int r = 0; r < 4; ++r) {
                    float v = fmaxf(cc[r] + bv, 0.0f);
                    int r16 = lq*4 + r;
                    areg[cch*512 + r16*32 + (((kc >> 3) ^ ((r16 >> 1) & 3))*8) + (kc & 7)]
                        = (_Float16)v;
                }
            }
        }
    };

    float4 ar0[4];
    if constexpr (ASRC == 1) stageA_load(0, ar0);      // oldest vmcnt entries
    if constexpr (MODE == 5) {
        // stage bd1 -> LDS (2048 f32 = 8 chunks of 1KB), before stage(0,0)
        #pragma unroll
        for (int c = wave; c < 8; c += NW)
            load_lds16(Xref + c*256 + lane*4, smem + 2*STRIDE + 2048 + c*512);
        const float* zf32 = (const float*)Ahp;
        const float* bz32 = (const float*)Cl;
        float4 b0 = *(const float4*)(bz32 + lq*8);
        float4 b1 = *(const float4*)(bz32 + lq*8 + 4);
        float bb[8] = {b0.x,b0.y,b0.z,b0.w,b1.x,b1.y,b1.z,b1.w};
        #pragma unroll
        for (int i2 = 0; i2 < TM; ++i2) {
            const float* zsrc = zf32 + (size_t)(bm0 + (wm*TM + i2)*16 + lrow)*32 + lq*8;
            float4 z0 = *(const float4*)(zsrc);
            float4 z1 = *(const float4*)(zsrc + 4);
            float zz[8] = {z0.x,z0.y,z0.z,z0.w,z1.x,z1.y,z1.z,z1.w};
            #pragma unroll
            for (int q = 0; q < 8; ++q) zfr[i2][q] = (_Float16)(zz[q] + bb[q]);
        }
    }
    stage(0, 0);
    if constexpr (ASRC == 1) {
        __builtin_amdgcn_s_waitcnt(0x0F70 | NPW_B);    // A-reg(0) landed; B(0) may fly
        stageA_write(0, ar0);
        asm volatile("s_waitcnt lgkmcnt(0)" ::: "memory");  // publish before 1st barrier
    }
    if constexpr (MODE == 5) {
        __builtin_amdgcn_s_waitcnt(0x0F70);            // vmcnt(0): bias+W(0)+B(0) landed
        __builtin_amdgcn_s_barrier();
        computeA(0, 0);                                // A(0) into stage-0 A region
        asm volatile("s_waitcnt lgkmcnt(0)" ::: "memory");
        __builtin_amdgcn_s_barrier();                  // A(0) visible to all waves
    }

    const int steps = K >> 5;
    for (int i = 0; i < steps; ++i) {
        const int sel = i & 1;
        float4 arn[4];
        if (i + 1 < steps) {
            if constexpr (ASRC == 1) stageA_load((i + 1) << 5, arn);
            stage(sel ^ 1, (i + 1) << 5);                 // prefetch next stage
            __builtin_amdgcn_s_waitcnt(0x0F70 | NPW);     // drain current stage only
        } else {
            __builtin_amdgcn_s_waitcnt(0x0F70);
        }
        __builtin_amdgcn_s_barrier();                     // all waves' data visible

        const _Float16* base = smem + sel*STRIDE;
        h8 ah[TM], al[TM], bh[TN], bl[TN];
        #pragma unroll
        for (int i2 = 0; i2 < TM; ++i2) {
            int row = (wm*TM + i2)*16 + lrow;
            int off = row*32 + ((lq ^ sw)*8);
            ah[i2] = *(const h8*)(base + off);
            if (PL == 2) al[i2] = *(const h8*)(base + BM*32 + off);
        }
        #pragma unroll
        for (int j = 0; j < TN; ++j) {
            int row = (wn*TN + j)*16 + lrow;
            int off = row*32 + ((lq ^ sw)*8);
            bh[j] = *(const h8*)(base + PL*BM*32 + off);
            if (PL == 2) bl[j] = *(const h8*)(base + PL*BM*32 + BN*32 + off);
        }
        if constexpr (ASRC == 1) {
            if (i + 1 < steps) {
                // A-reg(next) are the oldest outstanding; B(next) stays in flight.
                __builtin_amdgcn_s_waitcnt(0x0F70 | NPW_B);
                stageA_write(sel ^ 1, arn);               // into next stage's A region
            }
        }
        if constexpr (MODE == 5) {
            if (i + 1 < steps) {
                // the W chunk was the FIRST of this iteration's NPW issues
                __builtin_amdgcn_s_waitcnt(0x0F70 | (NPW - 1));
                computeA(sel ^ 1, i + 1);                 // write A(next) into next stage
            }
        }
        #pragma unroll
        for (int i2 = 0; i2 < TM; ++i2)
            #pragma unroll
            for (int j = 0; j < TN; ++j)
                acc[i2][j] = __builtin_amdgcn_mfma_f32_16x16x32_f16(ah[i2], bh[j], acc[i2][j], 0, 0, 0);
        if (TERMS == 3) {
            #pragma unroll
            for (int i2 = 0; i2 < TM; ++i2)
                #pragma unroll
                for (int j = 0; j < TN; ++j)
                    acc[i2][j] = __builtin_amdgcn_mfma_f32_16x16x32_f16(ah[i2], bl[j], acc[i2][j], 0, 0, 0);
            #pragma unroll
            for (int i2 = 0; i2 < TM; ++i2)
                #pragma unroll
                for (int j = 0; j < TN; ++j)
                    acc[i2][j] = __builtin_amdgcn_mfma_f32_16x16x32_f16(al[i2], bh[j], acc[i2][j], 0, 0, 0);
        }
        if constexpr (MODE == 5 || ASRC == 1) {
            // publish this iteration's ds-written A(next) before the barrier
            asm volatile("s_waitcnt lgkmcnt(0)" ::: "memory");
        }
        __builtin_amdgcn_s_barrier();   // buffer consumed; next iter may prefetch into it
    }

    // ---- fused z-projection epilogue (MODE 4) ----
    if constexpr (MODE == 4) {
        static_assert(WN*16 == 32, "MODE 4 needs N2=32 across WN waves");
        static_assert(BM*BN <= STRIDE, "MODE 4 tile planes must fit smem");
        constexpr int PLANE = BM*BN;           // halves per plane
        constexpr int NC2 = BN/32;             // K2 chunks of 32
        constexpr int MF2 = TM;                // m-frags per wave (BM/(16*WM))
        const _Float16* Wh = (const _Float16*)Ch;
        const _Float16* Wl = (const _Float16*)Cl;
        _Float16* th = smem;
        _Float16* tl = smem + PLANE;

        // issue B2 (Wz^T chunk) loads early; independent of LDS
        const int n2 = wn*16 + lrow;           // 0..31
        h8 b2h[NC2], b2l[NC2];
        #pragma unroll
        for (int cc = 0; cc < NC2; ++cc) {
            size_t go = (size_t)n2*N + bn0 + cc*32 + lq*8;
            b2h[cc] = *(const h8*)(Wh + go);
            b2l[cc] = *(const h8*)(Wl + go);
        }

        // scatter bias+relu'd tile as hi/lo planes, layout [chunk][m][32] swizzled
        #pragma unroll
        for (int j = 0; j < TN; ++j) {
            int col = (wn*TN + j)*16 + lrow;   // k2 index 0..BN-1
            float bj = bias[bn0 + col];
            int c = col >> 5, kk = col & 31;
            #pragma unroll
            for (int i = 0; i < TM; ++i) {
                int m0 = (wm*TM + i)*16 + lq*4;
                #pragma unroll
                for (int r = 0; r < 4; ++r) {
                    float v = acc[i][j][r] + bj;
                    if (RELU) v = fmaxf(v, 0.0f);
                    int m = m0 + r;
                    int a = c*(BM*32) + m*32 + (((kk >> 3) ^ ((m >> 1) & 3))*8) + (kk & 7);
                    _Float16 hh = (_Float16)v;
                    th[a] = hh;
                    tl[a] = (_Float16)(v - (float)hh);
                }
            }
        }
        __syncthreads();

        f4 acc2[MF2];
        #pragma unroll
        for (int mf = 0; mf < MF2; ++mf) acc2[mf] = (f4)0.0f;
        #pragma unroll
        for (int mf = 0; mf < MF2; ++mf) {
            int mrow = (wm*TM + mf)*16 + lrow;
            #pragma unroll
            for (int cc = 0; cc < NC2; ++cc) {
                int off = cc*(BM*32) + mrow*32 + ((lq ^ sw)*8);
                h8 a2h = *(const h8*)(th + off);
                h8 a2l = *(const h8*)(tl + off);
                acc2[mf] = __builtin_amdgcn_mfma_f32_16x16x32_f16(a2h, b2h[cc], acc2[mf], 0, 0, 0);
                acc2[mf] = __builtin_amdgcn_mfma_f32_16x16x32_f16(a2h, b2l[cc], acc2[mf], 0, 0, 0);
                acc2[mf] = __builtin_amdgcn_mfma_f32_16x16x32_f16(a2l, b2h[cc], acc2[mf], 0, 0, 0);
            }
        }
        #pragma unroll
        for (int mf = 0; mf < MF2; ++mf) {
            int rb = bm0 + (wm*TM + mf)*16 + lq*4;
            #pragma unroll
            for (int r = 0; r < 4; ++r)
                atomicAdd(&Cf[(size_t)(rb + r)*32 + n2], acc2[mf][r]);
        }
        return;
    }

    // ---- epilogue ----
    float lsum = 0.0f;
    #pragma unroll
    for (int j = 0; j < TN; ++j) {
        int col = bn0 + (wn*TN + j)*16 + lrow;
        float bj = bias[col];
        #pragma unroll
        for (int i = 0; i < TM; ++i) {
            int rbase = bm0 + (wm*TM + i)*16 + lq*4;
            #pragma unroll
            for (int r = 0; r < 4; ++r) {
                float v = acc[i][j][r] + bj;
                if (RELU) v = fmaxf(v, 0.0f);
                size_t idx = (size_t)(rbase + r)*N + col;
                if (MODE == 2) {
                    float d = v - Xref[idx];
                    lsum = fmaf(d, d, lsum);
                } else if (MODE == 0) {
                    _Float16 hh = (_Float16)v;
                    __builtin_nontemporal_store(hh, &Ch[idx]);
                    __builtin_nontemporal_store((_Float16)(v - (float)hh), &Cl[idx]);
                } else if (MODE == 1) {
                    _Float16 hh = (_Float16)v;
                    __builtin_nontemporal_store(hh, &Ch[idx]);
                    __builtin_nontemporal_store(v, &Cf[idx]);
                } else {
                    __builtin_nontemporal_store((_Float16)v, &Ch[idx]);
                }
            }
        }
    }
    if (MODE == 2) {
        for (int off = 32; off > 0; off >>= 1) lsum += __shfl_down(lsum, off, 64);
        __syncthreads();
        float* sc = (float*)smem;
        if (lane == 0) sc[wave] = lsum;
        __syncthreads();
        if (tid == 0) {
            double t = 0.0;
            for (int w = 0; w < NW; ++w) t += (double)sc[w];
            atomicAdd(loss_acc, t);
        }
    }
}

// ---------------- block reduction helpers ----------------
__device__ __forceinline__ float blk_sum_f(float v, float* sh) {
    int tid = threadIdx.x;
    sh[tid] = v; __syncthreads();
    for (int s = 128; s > 0; s >>= 1) { if (tid < s) sh[tid] += sh[tid+s]; __syncthreads(); }
    float r = sh[0]; __syncthreads();
    return r;
}
__device__ __forceinline__ float blk_min_f(float v, float* sh) {
    int tid = threadIdx.x;
    sh[tid] = v; __syncthreads();
    for (int s = 128; s > 0; s >>= 1) { if (tid < s) sh[tid] = fminf(sh[tid], sh[tid+s]); __syncthreads(); }
    float r = sh[0]; __syncthreads();
    return r;
}

// ---------------- clustering pass: 4 threads per point (+ last-block finalize) ----------------
__global__ __launch_bounds__(256)
void cluster_pass(const float* __restrict__ z, const float* __restrict__ bz,
                  const float* __restrict__ t1,
                  const float* __restrict__ clusters,
                  float* __restrict__ D, float* __restrict__ ROWSUM,
                  float* __restrict__ pred_out, float* __restrict__ u_acc,
                  int* __restrict__ cnt, double* __restrict__ dbl,
                  float* __restrict__ f_out, int* __restrict__ blkctr)
{
    __shared__ __align__(16) float cl[KCL*33];
    __shared__ __align__(16) float Ds[64*KCL];    // D staging: 64 points x 100 k
    __shared__ float u_s[KCL];
    __shared__ int cnt_s[KCL];                    // per-block histogram (kills same-address
                                                  // device-atomic serialization: argmax bk is
                                                  // heavily skewed -> cnt[bk] was ~10-20K deep)
    __shared__ float swave[4];
    __shared__ float bzs[NZ_DIM];
    __shared__ int lastFlag;
    const int tid = threadIdx.x;
    const int lane = tid & 63;
    for (int i = tid; i < KCL*NZ_DIM; i += 256) cl[(i >> 5)*33 + (i & 31)] = clusters[i];
    if (tid < KCL) { u_s[tid] = 0.0f; cnt_s[tid] = 0; }
    if (tid < NZ_DIM) bzs[tid] = bz[tid];
    __syncthreads();

    const int p  = (blockIdx.x*256 + tid) >> 2;
    const int pl = tid >> 2;                      // point-in-block 0..63
    const int kg = tid & 3;

    float zr[NZ_DIM];
    const float a = t1[p*3+0]*0.01f, b = t1[p*3+1]*0.01f, c = t1[p*3+2]*0.01f;
    const float cm = a*b*c*0.99f + 1.0f;
    float mean = 0.0f;
    {   // vectorized z read (float4 x8), same accumulation order as scalar loop
        const float4* zv = (const float4*)(z + (size_t)p*NZ_DIM);
        #pragma unroll
        for (int u = 0; u < 8; ++u) {
            float4 v = zv[u];
            zr[u*4+0] = (v.x + bzs[u*4+0])*cm; mean += zr[u*4+0];
            zr[u*4+1] = (v.y + bzs[u*4+1])*cm; mean += zr[u*4+1];
            zr[u*4+2] = (v.z + bzs[u*4+2])*cm; mean += zr[u*4+2];
            zr[u*4+3] = (v.w + bzs[u*4+3])*cm; mean += zr[u*4+3];
        }
    }
    mean *= (1.0f/NZ_DIM);
    float var = 0.0f;
    #pragma unroll
    for (int i = 0; i < NZ_DIM; ++i) { float d = zr[i]-mean; var += d*d; }
    const float istd = 1.0f / sqrtf(var * (1.0f/(NZ_DIM-1)));
    #pragma unroll
    for (int i = 0; i < NZ_DIM; ++i) zr[i] = (zr[i]-mean)*istd;

    float vals[25];
    float rowsum = 0.0f, best = -1.0f; int bk = 0;
    #pragma unroll
    for (int j = 0; j < 25; ++j) {
        const int k = kg + 4*j;
        float d = 0.0f;
        #pragma unroll
        for (int i = 0; i < NZ_DIM; ++i) { float t = zr[i]-cl[k*33+i]; d = fmaf(t,t,d); }
        float val = 1e-5f + d;
        vals[j] = val;
        rowsum += val;
        if (val > best) { best = val; bk = k; }
        Ds[pl*KCL + k] = val;                     // stage to LDS (coalesced flush later)
    }
    rowsum += __shfl_xor(rowsum, 1);
    rowsum += __shfl_xor(rowsum, 2);
    #pragma unroll
    for (int m = 1; m <= 2; m <<= 1) {
        float ov = __shfl_xor(best, m);
        int   ok = __shfl_xor(bk, m);
        if (ov > best || (ov == best && ok < bk)) { best = ov; bk = ok; }
    }
    if (kg == 0) {
        pred_out[p] = (float)bk;
        atomicAdd(&cnt_s[bk], 1);                 // LDS histogram (was global atomic)
        ROWSUM[p] = rowsum;
    }

    // coalesced D flush: block's 64x100 slab as float4
    __syncthreads();
    {
        float4* dst = (float4*)(D + (size_t)blockIdx.x * (64*KCL));
        const float4* src = (const float4*)Ds;
        for (int q = tid; q < (64*KCL)/4; q += 256) dst[q] = src[q];
    }

    const float inv_rs = 1.0f/rowsum;
    float Sp = 0.0f;
    #pragma unroll
    for (int j = 0; j < 25; ++j) {
        float qv = vals[j]*inv_rs;
        float lq = logf(qv);
        float om = 1.0f - qv;
        Sp += sqrtf(-1.0f/(om*om*lq*(float)M_PTS));
        float qs = qv;
        qs += __shfl_xor(qs, 4);
        qs += __shfl_xor(qs, 8);
        qs += __shfl_xor(qs, 16);
        qs += __shfl_xor(qs, 32);
        if (lane < 4) atomicAdd(&u_s[lane + 4*j], qs);
    }
    for (int off = 32; off > 0; off >>= 1) Sp += __shfl_down(Sp, off, 64);
    if (lane == 0) swave[tid >> 6] = Sp;
    __syncthreads();
    if (tid < KCL) {
        atomicAdd(&u_acc[tid], u_s[tid]);
        int c2 = cnt_s[tid];
        if (c2) atomicAdd(&cnt[tid], c2);         // <=464 per address (was up to ~20K)
    }
    if (tid == 0) atomicAdd(&dbl[0], (double)(swave[0]+swave[1]+swave[2]+swave[3]));

    // ---- last-block finalize (was finalize_kernel) ----
    // NOTE: no __threadfence() — on multi-XCD gfx950 it forces an L2 wb/inv per
    // block (catastrophic). All cross-block data flows via device-scope atomics;
    // __syncthreads() drains vmcnt(0) for every thread before tid0 signals.
    __syncthreads();
    if (tid == 0) {
        int old = atomicAdd(blkctr, 1);
        lastFlag = (old == (int)gridDim.x - 1);
    }
    __syncthreads();
    if (!lastFlag) return;

    float* shF = cl;                         // reuse shared (13.2 KB >= 2 KB needed)
    double* shD = (double*)&cl[1024];        // 8B-aligned (cl is 16B-aligned)
    const bool act = (tid < KCL);
    const float S = (float)atomicAdd(&dbl[0], 0.0);   // coherent device-scope read

    float uv = act ? atomicAdd(&u_acc[tid], 0.0f) : 0.0f;
    float um = blk_sum_f(uv, shF) * (1.0f/KCL);
    float ud = act ? (uv - um) : 0.0f;
    float uvar = blk_sum_f(ud*ud, shF) * (1.0f/(KCL-1));
    float un = ud / sqrtf(uvar);
    float umin = blk_min_f(act ? un : 3.0e38f, shF);
    float ufin = un - umin + 0.001f;

    float vv = 0.0f;
    if (act) { int cc2 = atomicAdd(&cnt[tid], 0); if (cc2 < 1) cc2 = 1; vv = sqrtf((float)cc2) * S; }
    float vm = blk_sum_f(vv, shF) * (1.0f/KCL);
    float vd = act ? (vv - vm) : 0.0f;
    float vvar = blk_sum_f(vd*vd, shF) * (1.0f/(KCL-1));
    float vn = vd / sqrtf(vvar);
    float vmin = blk_min_f(act ? vn : 3.0e38f, shF);
    float vfin = vn - vmin + 0.001f;

    if (act) f_out[tid] = ufin + vfin + 1.0f;

    double dp = 0.0;
    for (int pair = tid; pair < KCL*KCL; pair += 256) {
        int i = pair / KCL, j = pair % KCL;
        float d = 0.0f;
        #pragma unroll
        for (int t2 = 0; t2 < NZ_DIM; ++t2) {
            float x = clusters[i*NZ_DIM+t2] - clusters[j*NZ_DIM+t2];
            d = fmaf(x, x, d);
        }
        dp += (double)d;
    }
    shD[tid] = dp; __syncthreads();
    for (int s = 128; s > 0; s >>= 1) { if (tid < s) shD[tid] += shD[tid+s]; __syncthreads(); }
    if (tid == 0) {
        dbl[3] = 0.01 * (double)(KCL*KCL - KCL) / shD[0];
    }
}

// ---------------- KL pass (+ last-block final loss) ----------------
__global__ __launch_bounds__(256)
void kl_pass(const float* __restrict__ D, const float* __restrict__ ROWSUM,
             const float* __restrict__ f, double* __restrict__ dbl,
             float* __restrict__ out, int* __restrict__ blkctr)
{
    __shared__ __align__(16) float Ds[64*KCL];
    __shared__ float fs[KCL], lfs[KCL];
    __shared__ float swave[4];
    __shared__ int lastFlag;
    const int tid = threadIdx.x;
    const int lane = tid & 63;
    // coalesced stage of this block's D slab
    {
        const float4* src = (const float4*)(D + (size_t)blockIdx.x * (64*KCL));
        float4* dst = (float4*)Ds;
        for (int q = tid; q < (64*KCL)/4; q += 256) dst[q] = src[q];
    }
    if (tid < KCL) { float fv = f[tid]; fs[tid] = fv; lfs[tid] = logf(fv); }
    __syncthreads();

    const int p  = (blockIdx.x*256 + tid) >> 2;
    const int pl = tid >> 2;
    const int kg = tid & 3;

    float vals[25];
    #pragma unroll
    for (int j = 0; j < 25; ++j) vals[j] = Ds[pl*KCL + kg + 4*j];

    float sv = 0.0f;
    #pragma unroll
    for (int j = 0; j < 25; ++j) { float v = vals[j]; sv += v*v/fs[kg + 4*j]; }
    sv += __shfl_xor(sv, 1);
    sv += __shfl_xor(sv, 2);

    const float rowsum = ROWSUM[p];
    const float lrs = logf(rowsum), lsv = logf(sv);
    const float inv_sv = 1.0f/sv;
    float klp = 0.0f;
    #pragma unroll
    for (int j = 0; j < 25; ++j) {
        const int k = kg + 4*j;
        float v = vals[j];
        float pv = v*v/fs[k]*inv_sv;
        klp += pv*(logf(v) - lfs[k] - lsv + lrs);
    }
    for (int off = 32; off > 0; off >>= 1) klp += __shfl_down(klp, off, 64);
    if (lane == 0) swave[tid >> 6] = klp;
    __syncthreads();
    if (tid == 0) atomicAdd(&dbl[1], (double)(swave[0]+swave[1]+swave[2]+swave[3]));

    // ---- last-block final loss (no threadfence; see cluster_pass note) ----
    __syncthreads();
    if (tid == 0) {
        int old = atomicAdd(blkctr, 1);
        lastFlag = (old == (int)gridDim.x - 1);
    }
    __syncthreads();
    if (!lastFlag) return;
    if (tid == 0) {
        double kl = atomicAdd(&dbl[1], 0.0) / (double)((size_t)M_PTS*KCL) * 0.01;
        double re = dbl[2] / (double)((size_t)M_PTS*1024);   // prior dispatch (xbar)
        out[0] = (float)(kl + re + dbl[3]);                  // dbl[3]: prior dispatch
    }
}

extern "C" void kernel_launch(void* const* d_in, const int* in_sizes, int n_in,
                              void* d_out, int out_size, void* d_ws, size_t ws_size,
                              hipStream_t stream)
{
    const float* x   = (const float*)d_in[0];
    const float* t1c = (const float*)d_in[1];
    const float* clu = (const float*)d_in[2];
    const float* We1 = (const float*)d_in[3];  const float* be1 = (const float*)d_in[4];
    const float* We2 = (const float*)d_in[5];  const float* be2 = (const float*)d_in[6];
    const float* We3 = (const float*)d_in[7];  const float* be3 = (const float*)d_in[8];
    const float* Wz  = (const float*)d_in[9];  const float* bz  = (const float*)d_in[10];
    const float* Wd1 = (const float*)d_in[11]; const float* bd1 = (const float*)d_in[12];
    const float* Wd2 = (const float*)d_in[13]; const float* bd2 = (const float*)d_in[14];
    const float* Wd3 = (const float*)d_in[15]; const float* bd3 = (const float*)d_in[16];
    const float* Wxb = (const float*)d_in[17]; const float* bxb = (const float*)d_in[18];
    float* out = (float*)d_out;

    const size_t M = M_PTS;
    _Float16* H = (_Float16*)d_ws;
    size_t o = 0;
    _Float16* BIGh = H + o; o += M*2048;   // unused by GEMMs now; kept for layout stability
    _Float16* BIGl = H + o; o += M*2048;   // unused; kept for layout stability
    _Float16* S1h  = H + o; o += M*512;    // h1 -> d2
    _Float16* S1l  = H + o; o += M*512;    // (dead after h3) -> D overlay
    _Float16* S2h  = H + o; o += M*512;    // h2 -> d3
    _Float16* S2l  = H + o; o += M*512;    // (dead after h3) -> ROWSUM overlay
    _Float16* Zh   = H + o; o += M*32;     // unused now; kept for layout stability
    _Float16* Zl   = H + o; o += M*32;     // unused; kept for layout stability
    _Float16* We1h = H + o; o += 512*1024; _Float16* We1l = H + o; o += 512*1024;
    _Float16* We2h = H + o; o += 512*512;  _Float16* We2l = H + o; o += 512*512;
    _Float16* We3h = H + o; o += 2048*512; _Float16* We3l = H + o; o += 2048*512;
    _Float16* Wzh  = H + o; o += 32*2048;  _Float16* Wzl  = H + o; o += 32*2048;
    _Float16* Wd1h = H + o; o += 2048*32;  _Float16* Wd1l = H + o; o += 2048*32;
    _Float16* Wd2h = H + o; o += 512*2048; _Float16* Wd2l = H + o; o += 512*2048;
    _Float16* Wd3h = H + o; o += 512*512;  _Float16* Wd3l = H + o; o += 512*512;
    _Float16* Wxbh = H + o; o += 1024*512; _Float16* Wxbl = H + o; o += 1024*512;
    float* fpr = (float*)(H + o);
    float* Zf  = fpr;        fpr += M*32;
    float* U   = fpr;        fpr += 128;
    float* F   = fpr;        fpr += 128;
    int*   CNT = (int*)fpr;  fpr += 128;
    double* DBL = (double*)(((uintptr_t)fpr + 15) & ~(uintptr_t)15);

    // last-block counters live in the CNT tail (zeroed by prep_weights)
    int* CTR_CL = CNT + 126;
    int* CTR_KL = CNT + 127;

    // D/ROWSUM overlay the dead encoder lo-planes (decoder never touches them)
    float* Dm  = (float*)S1l;
    float* RSm = (float*)S2l;

    // batched weight transpose+split (one launch) + folded zeroing of Zf/U/CNT/DBL
    {
        PrepW pa;
        const float* Ws[8]  = {We1, We2, We3, Wz, Wd1, Wd2, Wd3, Wxb};
        _Float16* Ths[8]    = {We1h, We2h, We3h, Wzh, Wd1h, Wd2h, Wd3h, Wxbh};
        _Float16* Tls[8]    = {We1l, We2l, We3l, Wzl, Wd1l, Wd2l, Wd3l, Wxbl};
        const int Ks[8]     = {1024, 512, 512, 2048, 32, 2048, 512, 512};
        const int Ns[8]     = {512, 512, 2048, 32, 2048, 512, 512, 1024};
        int acc = 0;
        for (int i = 0; i < 8; ++i) {
            pa.W[i] = Ws[i]; pa.Th[i] = Ths[i]; pa.Tl[i] = Tls[i];
            pa.K[i] = Ks[i]; pa.N[i] = Ns[i];
            pa.off[i] = acc;
            acc += (Ns[i] >> 5) * (Ks[i] >> 5);
        }
        pa.off[8] = acc;   // 3712
        prep_weights<<<acc, 256, 0, stream>>>(pa, Zf, U, CNT, DBL);
    }

    const int MB = M_PTS/128;  // 232
    // ---- encoder: f16x3 split precision (argmax-exact path) ----
    // L1: x split in-kernel (ASRC=1) — split_x dispatch eliminated
    gemm_sp<2,2,4,4,true ,0,3,1><<<dim3(4,  MB), 256, 0, stream>>>(nullptr, nullptr, We1h, We1l, be1, S1h, S1l, nullptr, x, nullptr, M, 512,  1024);
    gemm_sp<2,2,4,4,true ,0,3><<<dim3(4,  MB), 256, 0, stream>>>(S1h, S1l, We2h, We2l, be2, S2h, S2l, nullptr, nullptr, nullptr, M, 512,  512);
    // h3 GEMM with fused z-projection: no h3 materialization, z partials -> Zf atomics
    gemm_sp<2,2,4,4,true ,4,3><<<dim3(16, MB), 256, 0, stream>>>(S2h, S2l, We3h, We3l, be3, Wzh, Wzl, Zf, nullptr, nullptr, M, 2048, 512);
    // ---- decoder: plain f16 (feeds re_loss only) ----
    // d1 fused into d2 (MODE 5): A = relu((Zf+bz) @ Wd1 + bd1), z read as fp32+bias
    gemm_sp<2,2,4,4,true ,5,1><<<dim3(4,  MB), 256, 0, stream>>>((const _Float16*)Zf, Wd1h, Wd2h, nullptr, bd2, S1h, (_Float16*)bz, nullptr, bd1, nullptr, M, 512,  2048);
    gemm_sp<2,2,4,4,true ,3,1><<<dim3(4,  MB), 256, 0, stream>>>(S1h, nullptr, Wd3h, nullptr, bd3, S2h,  nullptr, nullptr, nullptr, nullptr, M, 512,  512);
    gemm_sp<2,2,4,4,false,2,1><<<dim3(8,  MB), 256, 0, stream>>>(S2h, nullptr, Wxbh, nullptr, bxb, nullptr, nullptr, nullptr, x, DBL+2, M, 1024, 512);

    const int PB = (M_PTS*4)/256;   // 464 blocks, 4 threads/point
    cluster_pass<<<PB, 256, 0, stream>>>(Zf, bz, t1c, clu, Dm, RSm, out, U, CNT, DBL, F, CTR_CL);
    kl_pass<<<PB, 256, 0, stream>>>(Dm, RSm, F, DBL, out + M_PTS, CTR_KL);
}

// Round 9
// 937.149 us; speedup vs baseline: 1.2988x; 1.1254x over previous
//
#include <hip/hip_runtime.h>
#include <math.h>

#define M_PTS 29696
#define KCL 100
#define NZ_DIM 32
#define ASTR 256   // accumulator channel-spread stride (floats/ints; 1 KB)

typedef _Float16 h8 __attribute__((ext_vector_type(8)));
typedef _Float16 h4 __attribute__((ext_vector_type(4)));
typedef float f4 __attribute__((ext_vector_type(4)));

// async global->LDS, 16B per lane; LDS dest is wave-uniform base + lane*16
__device__ __forceinline__ void load_lds16(const void* g, void* l) {
    __builtin_amdgcn_global_load_lds(
        (const __attribute__((address_space(1))) void*)g,
        (__attribute__((address_space(3))) void*)l, 16, 0, 0);
}

// ---------------- batched weight transpose+split (+ folded accumulator zeroing) ----------------
// W (KxN) fp32 -> WTh/WTl (NxK) f16 hi/lo planes, all 8 weights in one launch.
struct PrepW {
    const float* W[8];
    _Float16* Th[8];
    _Float16* Tl[8];
    int K[8];
    int N[8];
    int off[9];   // cumulative 32x32-tile counts, off[0]=0
};

__global__ __launch_bounds__(256)
void prep_weights(PrepW a, float* __restrict__ Zf, float* __restrict__ US,
                  int* __restrict__ CS, int* __restrict__ CTRS,
                  double* __restrict__ DBL)
{
    __shared__ float t[32][33];
    const int bid = blockIdx.x;
    const int tid = threadIdx.x;

    // folded zeroing: first 928 blocks cover Zf (29696*32 floats) exactly
    if (bid < (M_PTS*NZ_DIM/4/256)) {
        const size_t zi = ((size_t)bid*256 + tid)*4;
        *(float4*)(Zf + zi) = make_float4(0.0f, 0.0f, 0.0f, 0.0f);
    }
    if (bid == 0) {
        if (tid < KCL) { US[tid*ASTR] = 0.0f; CS[tid*ASTR] = 0; }   // channel-spread accums
        if (tid == KCL) { CTRS[0] = 0; CTRS[1] = 0; }               // last-block counters
        if (tid < 8) DBL[tid] = 0.0;
    }

    int w = 0;
    #pragma unroll
    for (int i = 1; i < 8; ++i) w += (bid >= a.off[i]);
    const int local = bid - a.off[w];
    const int K = a.K[w], N = a.N[w];
    const int tx = N >> 5;                       // tiles along N (power of 2)
    const int sh = __builtin_ctz(tx);
    const int n0 = (local & (tx - 1)) * 32, k0 = (local >> sh) * 32;
    const float* W = a.W[w];
    _Float16* WTh = a.Th[w];
    _Float16* WTl = a.Tl[w];

    {
        int r = tid / 8, c = (tid % 8) * 4;
        const float4 v = *(const float4*)(W + (size_t)(k0 + r) * N + n0 + c);
        t[r][c+0] = v.x; t[r][c+1] = v.y; t[r][c+2] = v.z; t[r][c+3] = v.w;
    }
    __syncthreads();
    {
        int r = tid / 8, c = (tid % 8) * 4;   // r = n idx, c = k idx
        h4 hi, lo;
        #pragma unroll
        for (int u = 0; u < 4; ++u) {
            float f = t[c+u][r];
            _Float16 h = (_Float16)f;
            hi[u] = h; lo[u] = (_Float16)(f - (float)h);
        }
        *(h4*)(WTh + (size_t)(n0 + r) * K + k0 + c) = hi;
        *(h4*)(WTl + (size_t)(n0 + r) * K + k0 + c) = lo;
    }
}

// ---------------- MFMA GEMM, async double-buffered LDS ----------------
// A planes: MxK f16; B planes: NxK f16. C = act(A@B^T + bias).
// TERMS=3: split-precision (hi*hi + hi*lo + lo*hi), PL=2 planes staged.
// TERMS=1: plain f16, PL=1.
// MODE 0: write hi+lo. MODE 1: hi + fp32. MODE 2: fused re-loss. MODE 3: hi only.
// MODE 4: no C write; fused z-projection: atomicAdd(Cf, relu(C+bias) @ Wz^T chunk),
//         with Ch/Cl reinterpreted as Wz^T hi/lo planes (32 x N layout, stride N).
// MODE 5: fused-A decoder: A = relu(Z @ Wd1 + bd1) computed in-kernel per K-step.
//         Ahp = Zf (Mx32 fp32, cast), Cl = bz (fp32, cast), Alp = Wd1h, Xref = bd1.
// ASRC 1: A staged from fp32 Xref (MxK), split hi/lo in-kernel (reg-staged,
//         T14 async split: load early, ds_write after barrier). Same LDS layout.
template<int WM,int WN,int TM,int TN,bool RELU,int MODE,int TERMS,int ASRC=0>
__global__ __launch_bounds__(WM*WN*64)
void gemm_sp(const _Float16* __restrict__ Ahp, const _Float16* __restrict__ Alp,
             const _Float16* __restrict__ Bhp, const _Float16* __restrict__ Blp,
             const float* __restrict__ bias,
             _Float16* __restrict__ Ch, _Float16* __restrict__ Cl,
             float* __restrict__ Cf, const float* __restrict__ Xref,
             double* __restrict__ loss_acc,
             int M, int N, int K)
{
    constexpr int BM = WM*TM*16, BN = WN*TN*16, NW = WM*WN;
    constexpr int PL = (TERMS == 3) ? 2 : 1;
    constexpr int CA = BM/16, CB = BN/16;          // 1KB chunks
    constexpr int STRIDE = PL*(BM+BN)*32;          // halves per stage
    // per-wave vmcnt-counted issues per stage (uniform across waves).
    // ASRC=1: the 4 A-reg float4 loads occupy the same count the A asyncs did.
    constexpr int NPW = ((MODE == 5) ? 1 : (CA/NW)*PL)
                      + ((CB >= NW) ? (CB/NW) : 1)*PL;
    constexpr int NPW_B = ((CB >= NW) ? (CB/NW) : 1)*PL;   // B-only in-flight bound
    static_assert(ASRC == 0 || (TERMS == 3 && (CA/NW) == 2 && MODE == 0),
                  "ASRC=1 path sized for the L1 config");
    // MODE5 extra LDS: wd1 chunk dbuf (2x1024 halves) + bd1 bias (2048 f32 = 4096 halves)
    constexpr int EXTRA = (MODE == 5) ? (2048 + 4096) : 0;
    __shared__ __align__(16) _Float16 smem[2*STRIDE + EXTRA];

    const int tid = threadIdx.x;
    const int wave = tid >> 6, lane = tid & 63;
    const int wm = wave / WN, wn = wave % WN;
    const int lrow = lane & 15, lq = lane >> 4;
    const int sw = (lrow >> 1) & 3;                // bank swizzle
    const int lr4 = lane >> 2, lc4 = lane & 3;     // staging row-in-chunk / 16B col
    const int bm0 = blockIdx.y * BM, bn0 = blockIdx.x * BN;

    f4 acc[TM][TN];
    #pragma unroll
    for (int i = 0; i < TM; ++i)
        #pragma unroll
        for (int j = 0; j < TN; ++j)
            acc[i][j] = (f4)0.0f;

    auto stage = [&](int s, int k0) {
        _Float16* base = smem + s*STRIDE;
        if constexpr (MODE == 5) {
            // Wd1 chunk for this K-step: 32 rows x 32 halves; per wave its wn-half (1KB).
            // Issued FIRST so the mid-loop vmcnt(NPW-1) guarantees its arrival.
            int r_in = lane >> 2;                        // 0..15
            int gk = (lane & 3) ^ ((r_in >> 1) & 3);     // same k-group swizzle as A staging
            load_lds16(Alp + (size_t)(k0 + wn*16 + r_in)*32 + gk*8,
                       smem + 2*STRIDE + s*1024 + wn*512);
        } else if constexpr (ASRC == 1) {
            // A staged via reg path (see stageA_*); nothing async here.
        } else {
            #pragma unroll
            for (int c = wave; c < CA; c += NW) {
                int r = c*16 + lr4;
                int g = lc4 ^ ((r >> 1) & 3);
                size_t goff = (size_t)(bm0 + r)*K + k0 + g*8;
                load_lds16(Ahp + goff, base + c*512);
                if (PL == 2) load_lds16(Alp + goff, base + BM*32 + c*512);
            }
        }
        if (CB >= NW) {
            #pragma unroll
            for (int c = wave; c < CB; c += NW) {
                int r = c*16 + lr4;
                int g = lc4 ^ ((r >> 1) & 3);
                size_t goff = (size_t)(bn0 + r)*K + k0 + g*8;
                load_lds16(Bhp + goff, base + PL*BM*32 + c*512);
                if (PL == 2) load_lds16(Blp + goff, base + PL*BM*32 + BN*32 + c*512);
            }
        } else {  // fewer B chunks than waves: duplicate issues keep counts uniform
            int c = wave % CB;
            int r = c*16 + lr4;
            int g = lc4 ^ ((r >> 1) & 3);
            size_t goff = (size_t)(bn0 + r)*K + k0 + g*8;
            load_lds16(Bhp + goff, base + PL*BM*32 + c*512);
            if (PL == 2) load_lds16(Blp + goff, base + PL*BM*32 + BN*32 + c*512);
        }
    };

    // ---- ASRC=1: fp32 A-split staging (reg-staged, async-split) ----
    auto stageA_load = [&](int k0, float4 (&ar)[4]) {
        if constexpr (ASRC == 1) {
            #pragma unroll
            for (int u = 0; u < 2; ++u) {              // chunks c = wave + u*NW
                int c = wave + u*NW;
                int r = c*16 + lr4;
                int g = lc4 ^ ((r >> 1) & 3);
                const float* src = Xref + (size_t)(bm0 + r)*K + k0 + g*8;
                ar[u*2+0] = *(const float4*)(src);
                ar[u*2+1] = *(const float4*)(src + 4);
            }
        }
    };
    auto stageA_write = [&](int s, const float4 (&ar)[4]) {
        if constexpr (ASRC == 1) {
            _Float16* base = smem + s*STRIDE;
            #pragma unroll
            for (int u = 0; u < 2; ++u) {
                int c = wave + u*NW;
                float fv[8] = {ar[u*2].x, ar[u*2].y, ar[u*2].z, ar[u*2].w,
                               ar[u*2+1].x, ar[u*2+1].y, ar[u*2+1].z, ar[u*2+1].w};
                h8 hi, lo;
                #pragma unroll
                for (int q = 0; q < 8; ++q) {
                    _Float16 h = (_Float16)fv[q];
                    hi[q] = h; lo[q] = (_Float16)(fv[q] - (float)h);
                }
                // identical layout to the async path: chunk base + lane*16B
                *(h8*)(base + c*512 + lane*8) = hi;
                *(h8*)(base + BM*32 + c*512 + lane*8) = lo;
            }
        }
    };

    // MODE5: z fragments (loop-invariant A rows of the inner d1 matmul), built from
    // fp32 Zf + bz (bitwise-identical to the old finish_z staged f16 plane).
    h8 zfr[(MODE == 5) ? TM : 1];
    auto computeA = [&](int ds, int s) {
        if constexpr (MODE == 5) {
            const _Float16* wslot = smem + 2*STRIDE + ds*1024 + wn*512;
            const float* bds = (const float*)(smem + 2*STRIDE + 2048);
            h8 wf = *(const h8*)(wslot + lrow*32 + ((lq ^ sw)*8));
            float bv = bds[s*32 + wn*16 + lrow];
            _Float16* areg = smem + ds*STRIDE;
            const int kc = wn*16 + lrow;               // d1-col within the 32-chunk
            #pragma unroll
            for (int i2 = 0; i2 < TM; ++i2) {
                f4 cc = __builtin_amdgcn_mfma_f32_16x16x32_f16(zfr[i2], wf, (f4)0.0f, 0, 0, 0);
                int cch = wm*TM + i2;
                #pragma unroll
                for (int r = 0; r < 4; ++r) {
                    float v = fmaxf(cc[r] + bv, 0.0f);
                    int r16 = lq*4 + r;
                    areg[cch*512 + r16*32 + (((kc >> 3) ^ ((r16 >> 1) & 3))*8) + (kc & 7)]
                        = (_Float16)v;
                }
            }
        }
    };

    float4 ar0[4];
    if constexpr (ASRC == 1) stageA_load(0, ar0);      // oldest vmcnt entries
    if constexpr (MODE == 5) {
        // stage bd1 -> LDS (2048 f32 = 8 chunks of 1KB), before stage(0,0)
        #pragma unroll
        for (int c = wave; c < 8; c += NW)
            load_lds16(Xref + c*256 + lane*4, smem + 2*STRIDE + 2048 + c*512);
        const float* zf32 = (const float*)Ahp;
        const float* bz32 = (const float*)Cl;
        float4 b0 = *(const float4*)(bz32 + lq*8);
        float4 b1 = *(const float4*)(bz32 + lq*8 + 4);
        float bb[8] = {b0.x,b0.y,b0.z,b0.w,b1.x,b1.y,b1.z,b1.w};
        #pragma unroll
        for (int i2 = 0; i2 < TM; ++i2) {
            const float* zsrc = zf32 + (size_t)(bm0 + (wm*TM + i2)*16 + lrow)*32 + lq*8;
            float4 z0 = *(const float4*)(zsrc);
            float4 z1 = *(const float4*)(zsrc + 4);
            float zz[8] = {z0.x,z0.y,z0.z,z0.w,z1.x,z1.y,z1.z,z1.w};
            #pragma unroll
            for (int q = 0; q < 8; ++q) zfr[i2][q] = (_Float16)(zz[q] + bb[q]);
        }
    }
    stage(0, 0);
    if constexpr (ASRC == 1) {
        __builtin_amdgcn_s_waitcnt(0x0F70 | NPW_B);    // A-reg(0) landed; B(0) may fly
        stageA_write(0, ar0);
        asm volatile("s_waitcnt lgkmcnt(0)" ::: "memory");  // publish before 1st barrier
    }
    if constexpr (MODE == 5) {
        __builtin_amdgcn_s_waitcnt(0x0F70);            // vmcnt(0): bias+W(0)+B(0) landed
        __builtin_amdgcn_s_barrier();
        computeA(0, 0);                                // A(0) into stage-0 A region
        asm volatile("s_waitcnt lgkmcnt(0)" ::: "memory");
        __builtin_amdgcn_s_barrier();                  // A(0) visible to all waves
    }

    const int steps = K >> 5;
    for (int i = 0; i < steps; ++i) {
        const int sel = i & 1;
        float4 arn[4];
        if (i + 1 < steps) {
            if constexpr (ASRC == 1) stageA_load((i + 1) << 5, arn);
            stage(sel ^ 1, (i + 1) << 5);                 // prefetch next stage
            __builtin_amdgcn_s_waitcnt(0x0F70 | NPW);     // drain current stage only
        } else {
            __builtin_amdgcn_s_waitcnt(0x0F70);
        }
        __builtin_amdgcn_s_barrier();                     // all waves' data visible

        const _Float16* base = smem + sel*STRIDE;
        h8 ah[TM], al[TM], bh[TN], bl[TN];
        #pragma unroll
        for (int i2 = 0; i2 < TM; ++i2) {
            int row = (wm*TM + i2)*16 + lrow;
            int off = row*32 + ((lq ^ sw)*8);
            ah[i2] = *(const h8*)(base + off);
            if (PL == 2) al[i2] = *(const h8*)(base + BM*32 + off);
        }
        #pragma unroll
        for (int j = 0; j < TN; ++j) {
            int row = (wn*TN + j)*16 + lrow;
            int off = row*32 + ((lq ^ sw)*8);
            bh[j] = *(const h8*)(base + PL*BM*32 + off);
            if (PL == 2) bl[j] = *(const h8*)(base + PL*BM*32 + BN*32 + off);
        }
        if constexpr (ASRC == 1) {
            if (i + 1 < steps) {
                // A-reg(next) are the oldest outstanding; B(next) stays in flight.
                __builtin_amdgcn_s_waitcnt(0x0F70 | NPW_B);
                stageA_write(sel ^ 1, arn);               // into next stage's A region
            }
        }
        if constexpr (MODE == 5) {
            if (i + 1 < steps) {
                // the W chunk was the FIRST of this iteration's NPW issues
                __builtin_amdgcn_s_waitcnt(0x0F70 | (NPW - 1));
                computeA(sel ^ 1, i + 1);                 // write A(next) into next stage
            }
        }
        #pragma unroll
        for (int i2 = 0; i2 < TM; ++i2)
            #pragma unroll
            for (int j = 0; j < TN; ++j)
                acc[i2][j] = __builtin_amdgcn_mfma_f32_16x16x32_f16(ah[i2], bh[j], acc[i2][j], 0, 0, 0);
        if (TERMS == 3) {
            #pragma unroll
            for (int i2 = 0; i2 < TM; ++i2)
                #pragma unroll
                for (int j = 0; j < TN; ++j)
                    acc[i2][j] = __builtin_amdgcn_mfma_f32_16x16x32_f16(ah[i2], bl[j], acc[i2][j], 0, 0, 0);
            #pragma unroll
            for (int i2 = 0; i2 < TM; ++i2)
                #pragma unroll
                for (int j = 0; j < TN; ++j)
                    acc[i2][j] = __builtin_amdgcn_mfma_f32_16x16x32_f16(al[i2], bh[j], acc[i2][j], 0, 0, 0);
        }
        if constexpr (MODE == 5 || ASRC == 1) {
            // publish this iteration's ds-written A(next) before the barrier
            asm volatile("s_waitcnt lgkmcnt(0)" ::: "memory");
        }
        __builtin_amdgcn_s_barrier();   // buffer consumed; next iter may prefetch into it
    }

    // ---- fused z-projection epilogue (MODE 4) ----
    if constexpr (MODE == 4) {
        static_assert(WN*16 == 32, "MODE 4 needs N2=32 across WN waves");
        static_assert(BM*BN <= STRIDE, "MODE 4 tile planes must fit smem");
        constexpr int PLANE = BM*BN;           // halves per plane
        constexpr int NC2 = BN/32;             // K2 chunks of 32
        constexpr int MF2 = TM;                // m-frags per wave (BM/(16*WM))
        const _Float16* Wh = (const _Float16*)Ch;
        const _Float16* Wl = (const _Float16*)Cl;
        _Float16* th = smem;
        _Float16* tl = smem + PLANE;

        // issue B2 (Wz^T chunk) loads early; independent of LDS
        const int n2 = wn*16 + lrow;           // 0..31
        h8 b2h[NC2], b2l[NC2];
        #pragma unroll
        for (int cc = 0; cc < NC2; ++cc) {
            size_t go = (size_t)n2*N + bn0 + cc*32 + lq*8;
            b2h[cc] = *(const h8*)(Wh + go);
            b2l[cc] = *(const h8*)(Wl + go);
        }

        // scatter bias+relu'd tile as hi/lo planes, layout [chunk][m][32] swizzled
        #pragma unroll
        for (int j = 0; j < TN; ++j) {
            int col = (wn*TN + j)*16 + lrow;   // k2 index 0..BN-1
            float bj = bias[bn0 + col];
            int c = col >> 5, kk = col & 31;
            #pragma unroll
            for (int i = 0; i < TM; ++i) {
                int m0 = (wm*TM + i)*16 + lq*4;
                #pragma unroll
                for (int r = 0; r < 4; ++r) {
                    float v = acc[i][j][r] + bj;
                    if (RELU) v = fmaxf(v, 0.0f);
                    int m = m0 + r;
                    int a = c*(BM*32) + m*32 + (((kk >> 3) ^ ((m >> 1) & 3))*8) + (kk & 7);
                    _Float16 hh = (_Float16)v;
                    th[a] = hh;
                    tl[a] = (_Float16)(v - (float)hh);
                }
            }
        }
        __syncthreads();

        f4 acc2[MF2];
        #pragma unroll
        for (int mf = 0; mf < MF2; ++mf) acc2[mf] = (f4)0.0f;
        #pragma unroll
        for (int mf = 0; mf < MF2; ++mf) {
            int mrow = (wm*TM + mf)*16 + lrow;
            #pragma unroll
            for (int cc = 0; cc < NC2; ++cc) {
                int off = cc*(BM*32) + mrow*32 + ((lq ^ sw)*8);
                h8 a2h = *(const h8*)(th + off);
                h8 a2l = *(const h8*)(tl + off);
                acc2[mf] = __builtin_amdgcn_mfma_f32_16x16x32_f16(a2h, b2h[cc], acc2[mf], 0, 0, 0);
                acc2[mf] = __builtin_amdgcn_mfma_f32_16x16x32_f16(a2h, b2l[cc], acc2[mf], 0, 0, 0);
                acc2[mf] = __builtin_amdgcn_mfma_f32_16x16x32_f16(a2l, b2h[cc], acc2[mf], 0, 0, 0);
            }
        }
        #pragma unroll
        for (int mf = 0; mf < MF2; ++mf) {
            int rb = bm0 + (wm*TM + mf)*16 + lq*4;
            #pragma unroll
            for (int r = 0; r < 4; ++r)
                atomicAdd(&Cf[(size_t)(rb + r)*32 + n2], acc2[mf][r]);
        }
        return;
    }

    // ---- epilogue ----
    float lsum = 0.0f;
    #pragma unroll
    for (int j = 0; j < TN; ++j) {
        int col = bn0 + (wn*TN + j)*16 + lrow;
        float bj = bias[col];
        #pragma unroll
        for (int i = 0; i < TM; ++i) {
            int rbase = bm0 + (wm*TM + i)*16 + lq*4;
            #pragma unroll
            for (int r = 0; r < 4; ++r) {
                float v = acc[i][j][r] + bj;
                if (RELU) v = fmaxf(v, 0.0f);
                size_t idx = (size_t)(rbase + r)*N + col;
                if (MODE == 2) {
                    float d = v - Xref[idx];
                    lsum = fmaf(d, d, lsum);
                } else if (MODE == 0) {
                    _Float16 hh = (_Float16)v;
                    __builtin_nontemporal_store(hh, &Ch[idx]);
                    __builtin_nontemporal_store((_Float16)(v - (float)hh), &Cl[idx]);
                } else if (MODE == 1) {
                    _Float16 hh = (_Float16)v;
                    __builtin_nontemporal_store(hh, &Ch[idx]);
                    __builtin_nontemporal_store(v, &Cf[idx]);
                } else {
                    __builtin_nontemporal_store((_Float16)v, &Ch[idx]);
                }
            }
        }
    }
    if (MODE == 2) {
        for (int off = 32; off > 0; off >>= 1) lsum += __shfl_down(lsum, off, 64);
        __syncthreads();
        float* sc = (float*)smem;
        if (lane == 0) sc[wave] = lsum;
        __syncthreads();
        if (tid == 0) {
            double t = 0.0;
            for (int w = 0; w < NW; ++w) t += (double)sc[w];
            atomicAdd(loss_acc, t);
        }
    }
}

// ---------------- block reduction helpers ----------------
__device__ __forceinline__ float blk_sum_f(float v, float* sh) {
    int tid = threadIdx.x;
    sh[tid] = v; __syncthreads();
    for (int s = 128; s > 0; s >>= 1) { if (tid < s) sh[tid] += sh[tid+s]; __syncthreads(); }
    float r = sh[0]; __syncthreads();
    return r;
}
__device__ __forceinline__ float blk_min_f(float v, float* sh) {
    int tid = threadIdx.x;
    sh[tid] = v; __syncthreads();
    for (int s = 128; s > 0; s >>= 1) { if (tid < s) sh[tid] = fminf(sh[tid], sh[tid+s]); __syncthreads(); }
    float r = sh[0]; __syncthreads();
    return r;
}

// ---------------- clustering pass: 4 threads per point (+ last-block finalize) ----------------
__global__ __launch_bounds__(256)
void cluster_pass(const float* __restrict__ z, const float* __restrict__ bz,
                  const float* __restrict__ t1,
                  const float* __restrict__ clusters,
                  float* __restrict__ D, float* __restrict__ ROWSUM,
                  float* __restrict__ pred_out, float* __restrict__ u_acc,
                  int* __restrict__ cnt, double* __restrict__ dbl,
                  float* __restrict__ f_out, int* __restrict__ blkctr)
{
    __shared__ __align__(16) float cl[KCL*33];
    __shared__ __align__(16) float Ds[64*KCL];    // D staging: 64 points x 100 k
    __shared__ float u_s[KCL];
    __shared__ int cnt_s[KCL];                    // per-block histogram (argmax bk is skewed;
                                                  // direct cnt[bk] atomics were ~20K deep)
    __shared__ float swave[4];
    __shared__ float bzs[NZ_DIM];
    __shared__ int lastFlag;
    const int tid = threadIdx.x;
    const int lane = tid & 63;
    for (int i = tid; i < KCL*NZ_DIM; i += 256) cl[(i >> 5)*33 + (i & 31)] = clusters[i];
    if (tid < KCL) { u_s[tid] = 0.0f; cnt_s[tid] = 0; }
    if (tid < NZ_DIM) bzs[tid] = bz[tid];
    __syncthreads();

    const int p  = (blockIdx.x*256 + tid) >> 2;
    const int pl = tid >> 2;                      // point-in-block 0..63
    const int kg = tid & 3;

    float zr[NZ_DIM];
    const float a = t1[p*3+0]*0.01f, b = t1[p*3+1]*0.01f, c = t1[p*3+2]*0.01f;
    const float cm = a*b*c*0.99f + 1.0f;
    float mean = 0.0f;
    {   // vectorized z read (float4 x8), same accumulation order as scalar loop
        const float4* zv = (const float4*)(z + (size_t)p*NZ_DIM);
        #pragma unroll
        for (int u = 0; u < 8; ++u) {
            float4 v = zv[u];
            zr[u*4+0] = (v.x + bzs[u*4+0])*cm; mean += zr[u*4+0];
            zr[u*4+1] = (v.y + bzs[u*4+1])*cm; mean += zr[u*4+1];
            zr[u*4+2] = (v.z + bzs[u*4+2])*cm; mean += zr[u*4+2];
            zr[u*4+3] = (v.w + bzs[u*4+3])*cm; mean += zr[u*4+3];
        }
    }
    mean *= (1.0f/NZ_DIM);
    float var = 0.0f;
    #pragma unroll
    for (int i = 0; i < NZ_DIM; ++i) { float d = zr[i]-mean; var += d*d; }
    const float istd = 1.0f / sqrtf(var * (1.0f/(NZ_DIM-1)));
    #pragma unroll
    for (int i = 0; i < NZ_DIM; ++i) zr[i] = (zr[i]-mean)*istd;

    float vals[25];
    float rowsum = 0.0f, best = -1.0f; int bk = 0;
    #pragma unroll
    for (int j = 0; j < 25; ++j) {
        const int k = kg + 4*j;
        float d = 0.0f;
        #pragma unroll
        for (int i = 0; i < NZ_DIM; ++i) { float t = zr[i]-cl[k*33+i]; d = fmaf(t,t,d); }
        float val = 1e-5f + d;
        vals[j] = val;
        rowsum += val;
        if (val > best) { best = val; bk = k; }
        Ds[pl*KCL + k] = val;                     // stage to LDS (coalesced flush later)
    }
    rowsum += __shfl_xor(rowsum, 1);
    rowsum += __shfl_xor(rowsum, 2);
    #pragma unroll
    for (int m = 1; m <= 2; m <<= 1) {
        float ov = __shfl_xor(best, m);
        int   ok = __shfl_xor(bk, m);
        if (ov > best || (ov == best && ok < bk)) { best = ov; bk = ok; }
    }
    if (kg == 0) {
        pred_out[p] = (float)bk;
        atomicAdd(&cnt_s[bk], 1);                 // LDS histogram
        ROWSUM[p] = rowsum;
    }

    // coalesced D flush: block's 64x100 slab as float4
    __syncthreads();
    {
        float4* dst = (float4*)(D + (size_t)blockIdx.x * (64*KCL));
        const float4* src = (const float4*)Ds;
        for (int q = tid; q < (64*KCL)/4; q += 256) dst[q] = src[q];
    }

    const float inv_rs = 1.0f/rowsum;
    float Sp = 0.0f;
    #pragma unroll
    for (int j = 0; j < 25; ++j) {
        float qv = vals[j]*inv_rs;
        float lq = logf(qv);
        float om = 1.0f - qv;
        Sp += sqrtf(-1.0f/(om*om*lq*(float)M_PTS));
        float qs = qv;
        qs += __shfl_xor(qs, 4);
        qs += __shfl_xor(qs, 8);
        qs += __shfl_xor(qs, 16);
        qs += __shfl_xor(qs, 32);
        if (lane < 4) atomicAdd(&u_s[lane + 4*j], qs);
    }
    for (int off = 32; off > 0; off >>= 1) Sp += __shfl_down(Sp, off, 64);
    if (lane == 0) swave[tid >> 6] = Sp;
    __syncthreads();
    if (tid < KCL) {
        // channel-spread accumulators: u_acc[k*ASTR], cnt[k*ASTR] are 1 KB apart so
        // the 464x100 tail atomics drain through ~100 L2 channels instead of 1-2.
        atomicAdd(&u_acc[tid*ASTR], u_s[tid]);
        int c2 = cnt_s[tid];
        if (c2) atomicAdd(&cnt[tid*ASTR], c2);
    }
    if (tid == 0) atomicAdd(&dbl[0], (double)(swave[0]+swave[1]+swave[2]+swave[3]));

    // ---- last-block finalize (was finalize_kernel) ----
    // NOTE: no __threadfence() — on multi-XCD gfx950 it forces an L2 wb/inv per
    // block (catastrophic). All cross-block data flows via device-scope atomics;
    // __syncthreads() drains vmcnt(0) for every thread before tid0 signals.
    __syncthreads();
    if (tid == 0) {
        int old = atomicAdd(blkctr, 1);
        lastFlag = (old == (int)gridDim.x - 1);
    }
    __syncthreads();
    if (!lastFlag) return;

    float* shF = cl;                         // reuse shared (13.2 KB >= 2 KB needed)
    double* shD = (double*)&cl[1024];        // 8B-aligned (cl is 16B-aligned)
    const bool act = (tid < KCL);
    const float S = (float)atomicAdd(&dbl[0], 0.0);   // coherent device-scope read

    float uv = act ? atomicAdd(&u_acc[tid*ASTR], 0.0f) : 0.0f;
    float um = blk_sum_f(uv, shF) * (1.0f/KCL);
    float ud = act ? (uv - um) : 0.0f;
    float uvar = blk_sum_f(ud*ud, shF) * (1.0f/(KCL-1));
    float un = ud / sqrtf(uvar);
    float umin = blk_min_f(act ? un : 3.0e38f, shF);
    float ufin = un - umin + 0.001f;

    float vv = 0.0f;
    if (act) { int cc2 = atomicAdd(&cnt[tid*ASTR], 0); if (cc2 < 1) cc2 = 1; vv = sqrtf((float)cc2) * S; }
    float vm = blk_sum_f(vv, shF) * (1.0f/KCL);
    float vd = act ? (vv - vm) : 0.0f;
    float vvar = blk_sum_f(vd*vd, shF) * (1.0f/(KCL-1));
    float vn = vd / sqrtf(vvar);
    float vmin = blk_min_f(act ? vn : 3.0e38f, shF);
    float vfin = vn - vmin + 0.001f;

    if (act) f_out[tid] = ufin + vfin + 1.0f;

    double dp = 0.0;
    for (int pair = tid; pair < KCL*KCL; pair += 256) {
        int i = pair / KCL, j = pair % KCL;
        float d = 0.0f;
        #pragma unroll
        for (int t2 = 0; t2 < NZ_DIM; ++t2) {
            float x = clusters[i*NZ_DIM+t2] - clusters[j*NZ_DIM+t2];
            d = fmaf(x, x, d);
        }
        dp += (double)d;
    }
    shD[tid] = dp; __syncthreads();
    for (int s = 128; s > 0; s >>= 1) { if (tid < s) shD[tid] += shD[tid+s]; __syncthreads(); }
    if (tid == 0) {
        dbl[3] = 0.01 * (double)(KCL*KCL - KCL) / shD[0];
    }
}

// ---------------- KL pass (+ last-block final loss) ----------------
__global__ __launch_bounds__(256)
void kl_pass(const float* __restrict__ D, const float* __restrict__ ROWSUM,
             const float* __restrict__ f, double* __restrict__ dbl,
             float* __restrict__ out, int* __restrict__ blkctr)
{
    __shared__ __align__(16) float Ds[64*KCL];
    __shared__ float fs[KCL], lfs[KCL];
    __shared__ float swave[4];
    __shared__ int lastFlag;
    const int tid = threadIdx.x;
    const int lane = tid & 63;
    // coalesced stage of this block's D slab
    {
        const float4* src = (const float4*)(D + (size_t)blockIdx.x * (64*KCL));
        float4* dst = (float4*)Ds;
        for (int q = tid; q < (64*KCL)/4; q += 256) dst[q] = src[q];
    }
    if (tid < KCL) { float fv = f[tid]; fs[tid] = fv; lfs[tid] = logf(fv); }
    __syncthreads();

    const int p  = (blockIdx.x*256 + tid) >> 2;
    const int pl = tid >> 2;
    const int kg = tid & 3;

    float vals[25];
    #pragma unroll
    for (int j = 0; j < 25; ++j) vals[j] = Ds[pl*KCL + kg + 4*j];

    float sv = 0.0f;
    #pragma unroll
    for (int j = 0; j < 25; ++j) { float v = vals[j]; sv += v*v/fs[kg + 4*j]; }
    sv += __shfl_xor(sv, 1);
    sv += __shfl_xor(sv, 2);

    const float rowsum = ROWSUM[p];
    const float lrs = logf(rowsum), lsv = logf(sv);
    const float inv_sv = 1.0f/sv;
    float klp = 0.0f;
    #pragma unroll
    for (int j = 0; j < 25; ++j) {
        const int k = kg + 4*j;
        float v = vals[j];
        float pv = v*v/fs[k]*inv_sv;
        klp += pv*(logf(v) - lfs[k] - lsv + lrs);
    }
    for (int off = 32; off > 0; off >>= 1) klp += __shfl_down(klp, off, 64);
    if (lane == 0) swave[tid >> 6] = klp;
    __syncthreads();
    if (tid == 0) atomicAdd(&dbl[1], (double)(swave[0]+swave[1]+swave[2]+swave[3]));

    // ---- last-block final loss (no threadfence; see cluster_pass note) ----
    __syncthreads();
    if (tid == 0) {
        int old = atomicAdd(blkctr, 1);
        lastFlag = (old == (int)gridDim.x - 1);
    }
    __syncthreads();
    if (!lastFlag) return;
    if (tid == 0) {
        double kl = atomicAdd(&dbl[1], 0.0) / (double)((size_t)M_PTS*KCL) * 0.01;
        double re = dbl[2] / (double)((size_t)M_PTS*1024);   // prior dispatch (xbar)
        out[0] = (float)(kl + re + dbl[3]);                  // dbl[3]: prior dispatch
    }
}

extern "C" void kernel_launch(void* const* d_in, const int* in_sizes, int n_in,
                              void* d_out, int out_size, void* d_ws, size_t ws_size,
                              hipStream_t stream)
{
    const float* x   = (const float*)d_in[0];
    const float* t1c = (const float*)d_in[1];
    const float* clu = (const float*)d_in[2];
    const float* We1 = (const float*)d_in[3];  const float* be1 = (const float*)d_in[4];
    const float* We2 = (const float*)d_in[5];  const float* be2 = (const float*)d_in[6];
    const float* We3 = (const float*)d_in[7];  const float* be3 = (const float*)d_in[8];
    const float* Wz  = (const float*)d_in[9];  const float* bz  = (const float*)d_in[10];
    const float* Wd1 = (const float*)d_in[11]; const float* bd1 = (const float*)d_in[12];
    const float* Wd2 = (const float*)d_in[13]; const float* bd2 = (const float*)d_in[14];
    const float* Wd3 = (const float*)d_in[15]; const float* bd3 = (const float*)d_in[16];
    const float* Wxb = (const float*)d_in[17]; const float* bxb = (const float*)d_in[18];
    float* out = (float*)d_out;

    const size_t M = M_PTS;
    _Float16* H = (_Float16*)d_ws;
    size_t o = 0;
    _Float16* BIGh = H + o; o += M*2048;   // unused by GEMMs now; kept for layout stability
    _Float16* BIGl = H + o; o += M*2048;   // unused; kept for layout stability
    _Float16* S1h  = H + o; o += M*512;    // h1 -> d2
    _Float16* S1l  = H + o; o += M*512;    // (dead after h3) -> D overlay
    _Float16* S2h  = H + o; o += M*512;    // h2 -> d3
    _Float16* S2l  = H + o; o += M*512;    // (dead after h3) -> ROWSUM overlay
    _Float16* Zh   = H + o; o += M*32;     // unused now; kept for layout stability
    _Float16* Zl   = H + o; o += M*32;     // unused; kept for layout stability
    _Float16* We1h = H + o; o += 512*1024; _Float16* We1l = H + o; o += 512*1024;
    _Float16* We2h = H + o; o += 512*512;  _Float16* We2l = H + o; o += 512*512;
    _Float16* We3h = H + o; o += 2048*512; _Float16* We3l = H + o; o += 2048*512;
    _Float16* Wzh  = H + o; o += 32*2048;  _Float16* Wzl  = H + o; o += 32*2048;
    _Float16* Wd1h = H + o; o += 2048*32;  _Float16* Wd1l = H + o; o += 2048*32;
    _Float16* Wd2h = H + o; o += 512*2048; _Float16* Wd2l = H + o; o += 512*2048;
    _Float16* Wd3h = H + o; o += 512*512;  _Float16* Wd3l = H + o; o += 512*512;
    _Float16* Wxbh = H + o; o += 1024*512; _Float16* Wxbl = H + o; o += 1024*512;
    float* fpr = (float*)(H + o);
    float* Zf  = fpr;        fpr += M*32;
    float* US  = fpr;        fpr += KCL*ASTR;    // channel-spread u accumulator
    int*   CS  = (int*)fpr;  fpr += KCL*ASTR;    // channel-spread cnt accumulator
    float* F   = fpr;        fpr += 128;
    int*   CTRS = (int*)fpr; fpr += 16;          // last-block counters
    double* DBL = (double*)(((uintptr_t)fpr + 15) & ~(uintptr_t)15);

    // D/ROWSUM overlay the dead encoder lo-planes (decoder never touches them)
    float* Dm  = (float*)S1l;
    float* RSm = (float*)S2l;

    // batched weight transpose+split (one launch) + folded zeroing of Zf/US/CS/CTRS/DBL
    {
        PrepW pa;
        const float* Ws[8]  = {We1, We2, We3, Wz, Wd1, Wd2, Wd3, Wxb};
        _Float16* Ths[8]    = {We1h, We2h, We3h, Wzh, Wd1h, Wd2h, Wd3h, Wxbh};
        _Float16* Tls[8]    = {We1l, We2l, We3l, Wzl, Wd1l, Wd2l, Wd3l, Wxbl};
        const int Ks[8]     = {1024, 512, 512, 2048, 32, 2048, 512, 512};
        const int Ns[8]     = {512, 512, 2048, 32, 2048, 512, 512, 1024};
        int acc = 0;
        for (int i = 0; i < 8; ++i) {
            pa.W[i] = Ws[i]; pa.Th[i] = Ths[i]; pa.Tl[i] = Tls[i];
            pa.K[i] = Ks[i]; pa.N[i] = Ns[i];
            pa.off[i] = acc;
            acc += (Ns[i] >> 5) * (Ks[i] >> 5);
        }
        pa.off[8] = acc;   // 3712
        prep_weights<<<acc, 256, 0, stream>>>(pa, Zf, US, CS, CTRS, DBL);
    }

    const int MB = M_PTS/128;  // 232
    // ---- encoder: f16x3 split precision (argmax-exact path) ----
    // L1: x split in-kernel (ASRC=1) — split_x dispatch eliminated
    gemm_sp<2,2,4,4,true ,0,3,1><<<dim3(4,  MB), 256, 0, stream>>>(nullptr, nullptr, We1h, We1l, be1, S1h, S1l, nullptr, x, nullptr, M, 512,  1024);
    gemm_sp<2,2,4,4,true ,0,3><<<dim3(4,  MB), 256, 0, stream>>>(S1h, S1l, We2h, We2l, be2, S2h, S2l, nullptr, nullptr, nullptr, M, 512,  512);
    // h3 GEMM with fused z-projection: no h3 materialization, z partials -> Zf atomics
    gemm_sp<2,2,4,4,true ,4,3><<<dim3(16, MB), 256, 0, stream>>>(S2h, S2l, We3h, We3l, be3, Wzh, Wzl, Zf, nullptr, nullptr, M, 2048, 512);
    // ---- decoder: plain f16 (feeds re_loss only) ----
    // d1 fused into d2 (MODE 5): A = relu((Zf+bz) @ Wd1 + bd1), z read as fp32+bias
    gemm_sp<2,2,4,4,true ,5,1><<<dim3(4,  MB), 256, 0, stream>>>((const _Float16*)Zf, Wd1h, Wd2h, nullptr, bd2, S1h, (_Float16*)bz, nullptr, bd1, nullptr, M, 512,  2048);
    gemm_sp<2,2,4,4,true ,3,1><<<dim3(4,  MB), 256, 0, stream>>>(S1h, nullptr, Wd3h, nullptr, bd3, S2h,  nullptr, nullptr, nullptr, nullptr, M, 512,  512);
    gemm_sp<2,2,4,4,false,2,1><<<dim3(8,  MB), 256, 0, stream>>>(S2h, nullptr, Wxbh, nullptr, bxb, nullptr, nullptr, nullptr, x, DBL+2, M, 1024, 512);

    const int PB = (M_PTS*4)/256;   // 464 blocks, 4 threads/point
    cluster_pass<<<PB, 256, 0, stream>>>(Zf, bz, t1c, clu, Dm, RSm, out, US, CS, DBL, F, &CTRS[0]);
    kl_pass<<<PB, 256, 0, stream>>>(Dm, RSm, F, DBL, out + M_PTS, &CTRS[1]);
}